// Round 1
// baseline (817.532 us; speedup 1.0000x reference)
//
#include <hip/hip_runtime.h>
#include <hip/hip_bf16.h>

typedef __bf16 bf16x8 __attribute__((ext_vector_type(8)));
typedef float  f32x4  __attribute__((ext_vector_type(4)));
typedef unsigned short us8 __attribute__((ext_vector_type(8)));

__device__ inline unsigned short f2bf(float f) {
    unsigned u = __builtin_bit_cast(unsigned, f);
    u += 0x7fffu + ((u >> 16) & 1u);
    return (unsigned short)(u >> 16);
}

__device__ inline bf16x8 load_frag(const unsigned short* p) {
    return *reinterpret_cast<const bf16x8*>(p);
}

// ---------------- weight transpose + cast: in[K][N] fp32 -> out[N][K] bf16 ----------------
__global__ void transpose_cast(const float* __restrict__ in, unsigned short* __restrict__ out,
                               int K, int N) {
    __shared__ float tile[32][33];
    int k0 = blockIdx.y * 32, n0 = blockIdx.x * 32;
    int tx = threadIdx.x, ty = threadIdx.y;  // (32, 8)
#pragma unroll
    for (int i = 0; i < 4; ++i)
        tile[ty + 8 * i][tx] = in[(size_t)(k0 + ty + 8 * i) * N + n0 + tx];
    __syncthreads();
#pragma unroll
    for (int i = 0; i < 4; ++i)
        out[(size_t)(n0 + ty + 8 * i) * K + k0 + tx] = f2bf(tile[tx][ty + 8 * i]);
}

// ---------------- concat bq|bk|bv into one 1536 vector ----------------
__global__ void concat3(const float* __restrict__ a, const float* __restrict__ b,
                        const float* __restrict__ c, float* __restrict__ out) {
    int i = blockIdx.x * 256 + threadIdx.x;  // 1536 total
    float v = (i < 512) ? a[i] : ((i < 1024) ? b[i - 512] : c[i - 1024]);
    out[i] = v;
}

// ---------------- LayerNorm: fp32 [R][512] -> bf16 [R][512], 1 wave per row ----------------
__global__ __launch_bounds__(256) void ln_kernel(const float* __restrict__ x,
                                                 const float* __restrict__ w,
                                                 const float* __restrict__ b,
                                                 unsigned short* __restrict__ out) {
    int wave = threadIdx.x >> 6, lane = threadIdx.x & 63;
    size_t row = (size_t)blockIdx.x * 4 + wave;
    const float* xp = x + row * 512 + lane * 8;
    float4 v0 = *reinterpret_cast<const float4*>(xp);
    float4 v1 = *reinterpret_cast<const float4*>(xp + 4);
    float s = (v0.x + v0.y) + (v0.z + v0.w) + (v1.x + v1.y) + (v1.z + v1.w);
    float qq = v0.x * v0.x + v0.y * v0.y + v0.z * v0.z + v0.w * v0.w
             + v1.x * v1.x + v1.y * v1.y + v1.z * v1.z + v1.w * v1.w;
#pragma unroll
    for (int off = 1; off < 64; off <<= 1) {
        s += __shfl_xor(s, off, 64);
        qq += __shfl_xor(qq, off, 64);
    }
    float mu = s * (1.0f / 512.0f);
    float var = qq * (1.0f / 512.0f) - mu * mu;
    float rstd = rsqrtf(var + 1e-5f);
    int c = lane * 8;
    float4 w0 = *reinterpret_cast<const float4*>(w + c);
    float4 w1 = *reinterpret_cast<const float4*>(w + c + 4);
    float4 b0 = *reinterpret_cast<const float4*>(b + c);
    float4 b1 = *reinterpret_cast<const float4*>(b + c + 4);
    us8 r;
    r[0] = f2bf((v0.x - mu) * rstd * w0.x + b0.x);
    r[1] = f2bf((v0.y - mu) * rstd * w0.y + b0.y);
    r[2] = f2bf((v0.z - mu) * rstd * w0.z + b0.z);
    r[3] = f2bf((v0.w - mu) * rstd * w0.w + b0.w);
    r[4] = f2bf((v1.x - mu) * rstd * w1.x + b1.x);
    r[5] = f2bf((v1.y - mu) * rstd * w1.y + b1.y);
    r[6] = f2bf((v1.z - mu) * rstd * w1.z + b1.z);
    r[7] = f2bf((v1.w - mu) * rstd * w1.w + b1.w);
    *reinterpret_cast<us8*>(out + row * 512 + c) = r;
}

// ---------------- generic bf16 MFMA GEMM: C[M][N] = A[M][K] * BT[N][K]^T + bias ----------------
// EPI 0: bf16 store            (QKV)
// EPI 1: fp32 store = val+res  (x2 = x + o@wo + bo)
// EPI 2: bf16 store = GELU     (FF1)
// EPI 3: fp32 store = C += val (FF2, C holds x2)
template <int EPI>
__global__ __launch_bounds__(256) void gemm64(const unsigned short* __restrict__ A,
                                              const unsigned short* __restrict__ BT,
                                              const float* __restrict__ bias, void* Cout,
                                              const float* __restrict__ res, int M, int N, int K) {
    int lane = threadIdx.x & 63, wave = threadIdx.x >> 6;
    int quad = lane >> 4, l16 = lane & 15;
    int m0 = blockIdx.y * 64 + wave * 16;
    int n0 = blockIdx.x * 64;
    const unsigned short* ap = A + (size_t)(m0 + l16) * K + quad * 8;
    const unsigned short* bp = BT + (size_t)(n0 + l16) * K + quad * 8;
    f32x4 acc[4] = {};
    for (int k0 = 0; k0 < K; k0 += 32) {
        bf16x8 a = load_frag(ap + k0);
#pragma unroll
        for (int t = 0; t < 4; ++t) {
            bf16x8 b = load_frag(bp + (size_t)t * 16 * K + k0);
            acc[t] = __builtin_amdgcn_mfma_f32_16x16x32_bf16(a, b, acc[t], 0, 0, 0);
        }
    }
#pragma unroll
    for (int t = 0; t < 4; ++t) {
#pragma unroll
        for (int r = 0; r < 4; ++r) {
            int m = m0 + quad * 4 + r;
            int n = n0 + t * 16 + l16;
            float val = acc[t][r] + bias[n];
            size_t idx = (size_t)m * N + n;
            if (EPI == 0) {
                ((unsigned short*)Cout)[idx] = f2bf(val);
            } else if (EPI == 1) {
                ((float*)Cout)[idx] = val + res[idx];
            } else if (EPI == 2) {
                float g = 0.5f * val * (1.0f + erff(val * 0.70710678118654752f));
                ((unsigned short*)Cout)[idx] = f2bf(g);
            } else {
                ((float*)Cout)[idx] += val;
            }
        }
    }
}

// ---------------- flash attention: one WG = (b, h, 64 q-rows) ----------------
#define LPAD 72
__global__ __launch_bounds__(256) void attn_kernel(const unsigned short* __restrict__ qkv,
                                                   const float* __restrict__ bias,
                                                   unsigned short* __restrict__ o) {
    __shared__ unsigned short Ks[64][LPAD];
    __shared__ unsigned short VTs[64][LPAD];
    __shared__ unsigned short Ps[4][16][64];
    int tid = threadIdx.x;
    int lane = tid & 63, wave = tid >> 6, quad = lane >> 4, l16 = lane & 15;
    int qb = blockIdx.x, h = blockIdx.y, b = blockIdx.z;
    int qw = qb * 64 + wave * 16;  // wave's q base

    const unsigned short* qbase = qkv + ((size_t)(b * 2048 + qw + l16)) * 1536 + h * 64 + quad * 8;
    bf16x8 qf0 = load_frag(qbase);
    bf16x8 qf1 = load_frag(qbase + 32);

    f32x4 Oacc[4] = {};
    float mrow[4], lrow[4];
#pragma unroll
    for (int r = 0; r < 4; ++r) { mrow[r] = -1e30f; lrow[r] = 0.0f; }
    const float scale = 0.125f;  // 1/sqrt(64)

    int srow = tid >> 2;           // 0..63
    int sd0 = (tid & 3) * 16;      // 0,16,32,48
    const float* brow = bias + (size_t)h * 2048 * 2048;

    for (int kt = 0; kt < 32; ++kt) {
        int kb = kt * 64;
        __syncthreads();
        // stage K tile and V^T tile
        const unsigned short* kg = qkv + ((size_t)(b * 2048 + kb + srow)) * 1536 + 512 + h * 64 + sd0;
        const unsigned short* vg = kg + 512;
        *reinterpret_cast<uint4*>(&Ks[srow][sd0]) = *reinterpret_cast<const uint4*>(kg);
        *reinterpret_cast<uint4*>(&Ks[srow][sd0 + 8]) = *reinterpret_cast<const uint4*>(kg + 8);
        unsigned short vtmp[16];
        *reinterpret_cast<uint4*>(vtmp) = *reinterpret_cast<const uint4*>(vg);
        *reinterpret_cast<uint4*>(vtmp + 8) = *reinterpret_cast<const uint4*>(vg + 8);
#pragma unroll
        for (int j = 0; j < 16; ++j) VTs[sd0 + j][srow] = vtmp[j];
        __syncthreads();

        // S = Q K^T  (D layout: row = quad*4+r (q), col = l16 (k))
        float sv[4][4];
#pragma unroll
        for (int t = 0; t < 4; ++t) {
            f32x4 c = {};
            bf16x8 b0 = load_frag(&Ks[t * 16 + l16][quad * 8]);
            bf16x8 b1 = load_frag(&Ks[t * 16 + l16][32 + quad * 8]);
            c = __builtin_amdgcn_mfma_f32_16x16x32_bf16(qf0, b0, c, 0, 0, 0);
            c = __builtin_amdgcn_mfma_f32_16x16x32_bf16(qf1, b1, c, 0, 0, 0);
#pragma unroll
            for (int r = 0; r < 4; ++r) {
                int qg = qw + quad * 4 + r;
                int kc = kb + t * 16 + l16;
                sv[t][r] = c[r] * scale + brow[(size_t)qg * 2048 + kc];
            }
        }

        // online softmax (per row; rows live within a quad -> 16-lane reductions)
        float alpha[4];
#pragma unroll
        for (int r = 0; r < 4; ++r) {
            float mx = fmaxf(fmaxf(sv[0][r], sv[1][r]), fmaxf(sv[2][r], sv[3][r]));
#pragma unroll
            for (int off = 1; off < 16; off <<= 1) mx = fmaxf(mx, __shfl_xor(mx, off, 64));
            float mn = fmaxf(mrow[r], mx);
            alpha[r] = __expf(mrow[r] - mn);
            mrow[r] = mn;
            float rs = 0.0f;
#pragma unroll
            for (int t = 0; t < 4; ++t) {
                sv[t][r] = __expf(sv[t][r] - mn);
                rs += sv[t][r];
            }
#pragma unroll
            for (int off = 1; off < 16; off <<= 1) rs += __shfl_xor(rs, off, 64);
            lrow[r] = lrow[r] * alpha[r] + rs;
        }
#pragma unroll
        for (int t = 0; t < 4; ++t)
#pragma unroll
            for (int r = 0; r < 4; ++r) Oacc[t][r] *= alpha[r];

        // write P (C layout) to LDS for A-layout reload
#pragma unroll
        for (int t = 0; t < 4; ++t)
#pragma unroll
            for (int r = 0; r < 4; ++r) Ps[wave][quad * 4 + r][t * 16 + l16] = f2bf(sv[t][r]);
        __syncthreads();

        // O += P V
        bf16x8 pa0 = load_frag(&Ps[wave][l16][quad * 8]);
        bf16x8 pa1 = load_frag(&Ps[wave][l16][32 + quad * 8]);
#pragma unroll
        for (int t = 0; t < 4; ++t) {
            bf16x8 vb0 = load_frag(&VTs[t * 16 + l16][quad * 8]);
            bf16x8 vb1 = load_frag(&VTs[t * 16 + l16][32 + quad * 8]);
            Oacc[t] = __builtin_amdgcn_mfma_f32_16x16x32_bf16(pa0, vb0, Oacc[t], 0, 0, 0);
            Oacc[t] = __builtin_amdgcn_mfma_f32_16x16x32_bf16(pa1, vb1, Oacc[t], 0, 0, 0);
        }
    }

    // epilogue: O /= l, store bf16 at [b][q][h*64+d]
#pragma unroll
    for (int r = 0; r < 4; ++r) {
        float inv = 1.0f / lrow[r];
        int qg = qw + quad * 4 + r;
        unsigned short* op = o + ((size_t)(b * 2048 + qg)) * 512 + h * 64;
#pragma unroll
        for (int t = 0; t < 4; ++t) op[t * 16 + l16] = f2bf(Oacc[t][r] * inv);
    }
}

extern "C" void kernel_launch(void* const* d_in, const int* in_sizes, int n_in,
                              void* d_out, int out_size, void* d_ws, size_t ws_size,
                              hipStream_t stream) {
    const float* x      = (const float*)d_in[0];
    const float* abias  = (const float*)d_in[1];
    const float* ln1_w  = (const float*)d_in[2];
    const float* ln1_b  = (const float*)d_in[3];
    const float* ln2_w  = (const float*)d_in[4];
    const float* ln2_b  = (const float*)d_in[5];
    const float* wq     = (const float*)d_in[6];
    const float* bq     = (const float*)d_in[7];
    const float* wk     = (const float*)d_in[8];
    const float* bk     = (const float*)d_in[9];
    const float* wv     = (const float*)d_in[10];
    const float* bv     = (const float*)d_in[11];
    const float* wo     = (const float*)d_in[12];
    const float* bo     = (const float*)d_in[13];
    const float* w1     = (const float*)d_in[14];
    const float* b1     = (const float*)d_in[15];
    const float* w2     = (const float*)d_in[16];
    const float* b2     = (const float*)d_in[17];
    float* out = (float*)d_out;

    char* ws = (char*)d_ws;
    unsigned short* wqkvT  = (unsigned short*)(ws + 0);          // [1536][512] bf16
    unsigned short* woT    = (unsigned short*)(ws + 1572864);    // [512][512]
    unsigned short* w1T    = (unsigned short*)(ws + 2097152);    // [2048][512]
    unsigned short* w2T    = (unsigned short*)(ws + 4194304);    // [512][2048]
    float*          biasqkv= (float*)(ws + 6291456);             // [1536]
    unsigned short* hbuf   = (unsigned short*)(ws + 6297600);    // [8192][512] bf16 (h / h2)
    unsigned short* qkv    = (unsigned short*)(ws + 14686208);   // [8192][1536] bf16
    unsigned short* o_attn = (unsigned short*)(ws + 39852032);   // [8192][512] bf16
    unsigned short* ff1    = (unsigned short*)(ws + 48240640);   // [8192][2048] bf16

    dim3 tb(32, 8);
    transpose_cast<<<dim3(16, 16), tb, 0, stream>>>(wq, wqkvT, 512, 512);
    transpose_cast<<<dim3(16, 16), tb, 0, stream>>>(wk, wqkvT + 512 * 512, 512, 512);
    transpose_cast<<<dim3(16, 16), tb, 0, stream>>>(wv, wqkvT + 1024 * 512, 512, 512);
    transpose_cast<<<dim3(16, 16), tb, 0, stream>>>(wo, woT, 512, 512);
    transpose_cast<<<dim3(64, 16), tb, 0, stream>>>(w1, w1T, 512, 2048);
    transpose_cast<<<dim3(16, 64), tb, 0, stream>>>(w2, w2T, 2048, 512);
    concat3<<<6, 256, 0, stream>>>(bq, bk, bv, biasqkv);

    // h = LN1(x)
    ln_kernel<<<2048, 256, 0, stream>>>(x, ln1_w, ln1_b, hbuf);
    // qkv = h @ [wq|wk|wv] + [bq|bk|bv]
    gemm64<0><<<dim3(24, 128), 256, 0, stream>>>(hbuf, wqkvT, biasqkv, qkv, nullptr, 8192, 1536, 512);
    // o_attn = attention(q,k,v, bias)
    attn_kernel<<<dim3(32, 8, 4), 256, 0, stream>>>(qkv, abias, o_attn);
    // out(x2) = x + o_attn @ wo + bo
    gemm64<1><<<dim3(8, 128), 256, 0, stream>>>(o_attn, woT, bo, out, x, 8192, 512, 512);
    // h2 = LN2(x2)
    ln_kernel<<<2048, 256, 0, stream>>>(out, ln2_w, ln2_b, hbuf);
    // ff1 = GELU(h2 @ w1 + b1)
    gemm64<2><<<dim3(32, 128), 256, 0, stream>>>(hbuf, w1T, b1, ff1, nullptr, 8192, 2048, 512);
    // out = x2 + ff1 @ w2 + b2
    gemm64<3><<<dim3(8, 128), 256, 0, stream>>>(ff1, w2T, b2, out, nullptr, 8192, 512, 2048);
}

// Round 2
// 518.185 us; speedup vs baseline: 1.5777x; 1.5777x over previous
//
#include <hip/hip_runtime.h>
#include <hip/hip_bf16.h>

typedef __bf16 bf16x8 __attribute__((ext_vector_type(8)));
typedef float  f32x4  __attribute__((ext_vector_type(4)));
typedef unsigned short us8 __attribute__((ext_vector_type(8)));

__device__ inline unsigned short f2bf(float f) {
    unsigned u = __builtin_bit_cast(unsigned, f);
    u += 0x7fffu + ((u >> 16) & 1u);
    return (unsigned short)(u >> 16);
}

__device__ inline bf16x8 load_frag(const unsigned short* p) {
    return *reinterpret_cast<const bf16x8*>(p);
}

// async global->LDS, 16 bytes per lane (wave-uniform LDS base + lane*16)
__device__ inline void gload_lds16(const unsigned short* g, unsigned short* l) {
    __builtin_amdgcn_global_load_lds(
        (const __attribute__((address_space(1))) void*)g,
        (__attribute__((address_space(3))) void*)l, 16, 0, 0);
}

// ---------------- weight transpose + cast: in[K][N] fp32 -> out[N][K] bf16 ----------------
__global__ void transpose_cast(const float* __restrict__ in, unsigned short* __restrict__ out,
                               int K, int N) {
    __shared__ float tile[32][33];
    int k0 = blockIdx.y * 32, n0 = blockIdx.x * 32;
    int tx = threadIdx.x, ty = threadIdx.y;  // (32, 8)
#pragma unroll
    for (int i = 0; i < 4; ++i)
        tile[ty + 8 * i][tx] = in[(size_t)(k0 + ty + 8 * i) * N + n0 + tx];
    __syncthreads();
#pragma unroll
    for (int i = 0; i < 4; ++i)
        out[(size_t)(n0 + ty + 8 * i) * K + k0 + tx] = f2bf(tile[tx][ty + 8 * i]);
}

// ---------------- concat bq|bk|bv into one 1536 vector ----------------
__global__ void concat3(const float* __restrict__ a, const float* __restrict__ b,
                        const float* __restrict__ c, float* __restrict__ out) {
    int i = blockIdx.x * 256 + threadIdx.x;  // 1536 total
    float v = (i < 512) ? a[i] : ((i < 1024) ? b[i - 512] : c[i - 1024]);
    out[i] = v;
}

// ---------------- LayerNorm: fp32 [R][512] -> bf16 [R][512], 1 wave per row ----------------
__global__ __launch_bounds__(256) void ln_kernel(const float* __restrict__ x,
                                                 const float* __restrict__ w,
                                                 const float* __restrict__ b,
                                                 unsigned short* __restrict__ out) {
    int wave = threadIdx.x >> 6, lane = threadIdx.x & 63;
    size_t row = (size_t)blockIdx.x * 4 + wave;
    const float* xp = x + row * 512 + lane * 8;
    float4 v0 = *reinterpret_cast<const float4*>(xp);
    float4 v1 = *reinterpret_cast<const float4*>(xp + 4);
    float s = (v0.x + v0.y) + (v0.z + v0.w) + (v1.x + v1.y) + (v1.z + v1.w);
    float qq = v0.x * v0.x + v0.y * v0.y + v0.z * v0.z + v0.w * v0.w
             + v1.x * v1.x + v1.y * v1.y + v1.z * v1.z + v1.w * v1.w;
#pragma unroll
    for (int off = 1; off < 64; off <<= 1) {
        s += __shfl_xor(s, off, 64);
        qq += __shfl_xor(qq, off, 64);
    }
    float mu = s * (1.0f / 512.0f);
    float var = qq * (1.0f / 512.0f) - mu * mu;
    float rstd = rsqrtf(var + 1e-5f);
    int c = lane * 8;
    float4 w0 = *reinterpret_cast<const float4*>(w + c);
    float4 w1 = *reinterpret_cast<const float4*>(w + c + 4);
    float4 b0 = *reinterpret_cast<const float4*>(b + c);
    float4 b1 = *reinterpret_cast<const float4*>(b + c + 4);
    us8 r;
    r[0] = f2bf((v0.x - mu) * rstd * w0.x + b0.x);
    r[1] = f2bf((v0.y - mu) * rstd * w0.y + b0.y);
    r[2] = f2bf((v0.z - mu) * rstd * w0.z + b0.z);
    r[3] = f2bf((v0.w - mu) * rstd * w0.w + b0.w);
    r[4] = f2bf((v1.x - mu) * rstd * w1.x + b1.x);
    r[5] = f2bf((v1.y - mu) * rstd * w1.y + b1.y);
    r[6] = f2bf((v1.z - mu) * rstd * w1.z + b1.z);
    r[7] = f2bf((v1.w - mu) * rstd * w1.w + b1.w);
    *reinterpret_cast<us8*>(out + row * 512 + c) = r;
}

// ---------------- m97-style 128x128 MFMA GEMM: C[M][N] = A[M][K] * BT[N][K]^T + bias --------
// 256 threads = 4 waves in 2x2; BK=32; LDS staged via global_load_lds width 16.
// EPI 0: bf16 store            (QKV)
// EPI 1: fp32 store = val+res  (x2 = x + o@wo + bo)
// EPI 2: bf16 store = GELU     (FF1)
// EPI 3: fp32 store = C += val (FF2, C holds x2)
template <int EPI>
__global__ __launch_bounds__(256) void gemm128(const unsigned short* __restrict__ A,
                                               const unsigned short* __restrict__ BT,
                                               const float* __restrict__ bias, void* Cout,
                                               const float* __restrict__ res, int M, int N, int K) {
    __shared__ unsigned short As[128 * 32];
    __shared__ unsigned short Bs[128 * 32];
    int tid = threadIdx.x;
    int lane = tid & 63, wave = tid >> 6;
    int quad = lane >> 4, l16 = lane & 15;
    int wm = (wave >> 1) * 64, wn = (wave & 1) * 64;
    int m0 = blockIdx.y * 128, n0 = blockIdx.x * 128;

    // staging indices: chunk c covers row c>>2, k-segment (c&3)*8 (16 bytes)
    int c0 = tid, c1 = tid + 256;
    const unsigned short* ag0 = A + (size_t)(m0 + (c0 >> 2)) * K + (c0 & 3) * 8;
    const unsigned short* ag1 = A + (size_t)(m0 + (c1 >> 2)) * K + (c1 & 3) * 8;
    const unsigned short* bg0 = BT + (size_t)(n0 + (c0 >> 2)) * K + (c0 & 3) * 8;
    const unsigned short* bg1 = BT + (size_t)(n0 + (c1 >> 2)) * K + (c1 & 3) * 8;
    unsigned short* al0 = As + c0 * 8;
    unsigned short* al1 = As + c1 * 8;
    unsigned short* bl0 = Bs + c0 * 8;
    unsigned short* bl1 = Bs + c1 * 8;

    f32x4 acc[4][4] = {};
    for (int k0 = 0; k0 < K; k0 += 32) {
        __syncthreads();
        gload_lds16(ag0 + k0, al0);
        gload_lds16(ag1 + k0, al1);
        gload_lds16(bg0 + k0, bl0);
        gload_lds16(bg1 + k0, bl1);
        __syncthreads();
        bf16x8 af[4], bf[4];
#pragma unroll
        for (int i = 0; i < 4; ++i)
            af[i] = load_frag(As + (wm + i * 16 + l16) * 32 + quad * 8);
#pragma unroll
        for (int j = 0; j < 4; ++j)
            bf[j] = load_frag(Bs + (wn + j * 16 + l16) * 32 + quad * 8);
#pragma unroll
        for (int i = 0; i < 4; ++i)
#pragma unroll
            for (int j = 0; j < 4; ++j)
                acc[i][j] = __builtin_amdgcn_mfma_f32_16x16x32_bf16(af[i], bf[j], acc[i][j], 0, 0, 0);
    }

#pragma unroll
    for (int i = 0; i < 4; ++i) {
#pragma unroll
        for (int j = 0; j < 4; ++j) {
#pragma unroll
            for (int r = 0; r < 4; ++r) {
                int m = m0 + wm + i * 16 + quad * 4 + r;
                int n = n0 + wn + j * 16 + l16;
                float val = acc[i][j][r] + bias[n];
                size_t idx = (size_t)m * N + n;
                if (EPI == 0) {
                    ((unsigned short*)Cout)[idx] = f2bf(val);
                } else if (EPI == 1) {
                    ((float*)Cout)[idx] = val + res[idx];
                } else if (EPI == 2) {
                    float g = 0.5f * val * (1.0f + erff(val * 0.70710678118654752f));
                    ((unsigned short*)Cout)[idx] = f2bf(g);
                } else {
                    ((float*)Cout)[idx] += val;
                }
            }
        }
    }
}

// ---------------- flash attention: one WG = (b, h, 64 q-rows) ----------------
#define LPAD 72
__global__ __launch_bounds__(256) void attn_kernel(const unsigned short* __restrict__ qkv,
                                                   const float* __restrict__ bias,
                                                   unsigned short* __restrict__ o) {
    __shared__ unsigned short Ks[64][LPAD];
    __shared__ unsigned short VTs[64][LPAD];
    __shared__ unsigned short Ps[4][16][64];
    int tid = threadIdx.x;
    int lane = tid & 63, wave = tid >> 6, quad = lane >> 4, l16 = lane & 15;
    int qb = blockIdx.x, h = blockIdx.y, b = blockIdx.z;
    int qw = qb * 64 + wave * 16;  // wave's q base

    const unsigned short* qbase = qkv + ((size_t)(b * 2048 + qw + l16)) * 1536 + h * 64 + quad * 8;
    bf16x8 qf0 = load_frag(qbase);
    bf16x8 qf1 = load_frag(qbase + 32);

    f32x4 Oacc[4] = {};
    float mrow[4], lrow[4];
#pragma unroll
    for (int r = 0; r < 4; ++r) { mrow[r] = -1e30f; lrow[r] = 0.0f; }
    const float scale = 0.125f;  // 1/sqrt(64)

    int srow = tid >> 2;           // 0..63
    int sd0 = (tid & 3) * 16;      // 0,16,32,48
    const float* brow = bias + (size_t)h * 2048 * 2048;

    for (int kt = 0; kt < 32; ++kt) {
        int kb = kt * 64;
        __syncthreads();
        // stage K tile and V^T tile
        const unsigned short* kg = qkv + ((size_t)(b * 2048 + kb + srow)) * 1536 + 512 + h * 64 + sd0;
        const unsigned short* vg = kg + 512;
        *reinterpret_cast<uint4*>(&Ks[srow][sd0]) = *reinterpret_cast<const uint4*>(kg);
        *reinterpret_cast<uint4*>(&Ks[srow][sd0 + 8]) = *reinterpret_cast<const uint4*>(kg + 8);
        unsigned short vtmp[16];
        *reinterpret_cast<uint4*>(vtmp) = *reinterpret_cast<const uint4*>(vg);
        *reinterpret_cast<uint4*>(vtmp + 8) = *reinterpret_cast<const uint4*>(vg + 8);
#pragma unroll
        for (int j = 0; j < 16; ++j) VTs[sd0 + j][srow] = vtmp[j];
        __syncthreads();

        // S = Q K^T  (D layout: row = quad*4+r (q), col = l16 (k))
        float sv[4][4];
#pragma unroll
        for (int t = 0; t < 4; ++t) {
            f32x4 c = {};
            bf16x8 b0 = load_frag(&Ks[t * 16 + l16][quad * 8]);
            bf16x8 b1 = load_frag(&Ks[t * 16 + l16][32 + quad * 8]);
            c = __builtin_amdgcn_mfma_f32_16x16x32_bf16(qf0, b0, c, 0, 0, 0);
            c = __builtin_amdgcn_mfma_f32_16x16x32_bf16(qf1, b1, c, 0, 0, 0);
#pragma unroll
            for (int r = 0; r < 4; ++r) {
                int qg = qw + quad * 4 + r;
                int kc = kb + t * 16 + l16;
                sv[t][r] = c[r] * scale + brow[(size_t)qg * 2048 + kc];
            }
        }

        // online softmax (per row; rows live within a quad -> 16-lane reductions)
        float alpha[4];
#pragma unroll
        for (int r = 0; r < 4; ++r) {
            float mx = fmaxf(fmaxf(sv[0][r], sv[1][r]), fmaxf(sv[2][r], sv[3][r]));
#pragma unroll
            for (int off = 1; off < 16; off <<= 1) mx = fmaxf(mx, __shfl_xor(mx, off, 64));
            float mn = fmaxf(mrow[r], mx);
            alpha[r] = __expf(mrow[r] - mn);
            mrow[r] = mn;
            float rs = 0.0f;
#pragma unroll
            for (int t = 0; t < 4; ++t) {
                sv[t][r] = __expf(sv[t][r] - mn);
                rs += sv[t][r];
            }
#pragma unroll
            for (int off = 1; off < 16; off <<= 1) rs += __shfl_xor(rs, off, 64);
            lrow[r] = lrow[r] * alpha[r] + rs;
        }
#pragma unroll
        for (int t = 0; t < 4; ++t)
#pragma unroll
            for (int r = 0; r < 4; ++r) Oacc[t][r] *= alpha[r];

        // write P (C layout) to LDS for A-layout reload
#pragma unroll
        for (int t = 0; t < 4; ++t)
#pragma unroll
            for (int r = 0; r < 4; ++r) Ps[wave][quad * 4 + r][t * 16 + l16] = f2bf(sv[t][r]);
        __syncthreads();

        // O += P V
        bf16x8 pa0 = load_frag(&Ps[wave][l16][quad * 8]);
        bf16x8 pa1 = load_frag(&Ps[wave][l16][32 + quad * 8]);
#pragma unroll
        for (int t = 0; t < 4; ++t) {
            bf16x8 vb0 = load_frag(&VTs[t * 16 + l16][quad * 8]);
            bf16x8 vb1 = load_frag(&VTs[t * 16 + l16][32 + quad * 8]);
            Oacc[t] = __builtin_amdgcn_mfma_f32_16x16x32_bf16(pa0, vb0, Oacc[t], 0, 0, 0);
            Oacc[t] = __builtin_amdgcn_mfma_f32_16x16x32_bf16(pa1, vb1, Oacc[t], 0, 0, 0);
        }
    }

    // epilogue: O /= l, store bf16 at [b][q][h*64+d]
#pragma unroll
    for (int r = 0; r < 4; ++r) {
        float inv = 1.0f / lrow[r];
        int qg = qw + quad * 4 + r;
        unsigned short* op = o + ((size_t)(b * 2048 + qg)) * 512 + h * 64;
#pragma unroll
        for (int t = 0; t < 4; ++t) op[t * 16 + l16] = f2bf(Oacc[t][r] * inv);
    }
}

extern "C" void kernel_launch(void* const* d_in, const int* in_sizes, int n_in,
                              void* d_out, int out_size, void* d_ws, size_t ws_size,
                              hipStream_t stream) {
    const float* x      = (const float*)d_in[0];
    const float* abias  = (const float*)d_in[1];
    const float* ln1_w  = (const float*)d_in[2];
    const float* ln1_b  = (const float*)d_in[3];
    const float* ln2_w  = (const float*)d_in[4];
    const float* ln2_b  = (const float*)d_in[5];
    const float* wq     = (const float*)d_in[6];
    const float* bq     = (const float*)d_in[7];
    const float* wk     = (const float*)d_in[8];
    const float* bk     = (const float*)d_in[9];
    const float* wv     = (const float*)d_in[10];
    const float* bv     = (const float*)d_in[11];
    const float* wo     = (const float*)d_in[12];
    const float* bo     = (const float*)d_in[13];
    const float* w1     = (const float*)d_in[14];
    const float* b1     = (const float*)d_in[15];
    const float* w2     = (const float*)d_in[16];
    const float* b2     = (const float*)d_in[17];
    float* out = (float*)d_out;

    char* ws = (char*)d_ws;
    unsigned short* wqkvT  = (unsigned short*)(ws + 0);          // [1536][512] bf16
    unsigned short* woT    = (unsigned short*)(ws + 1572864);    // [512][512]
    unsigned short* w1T    = (unsigned short*)(ws + 2097152);    // [2048][512]
    unsigned short* w2T    = (unsigned short*)(ws + 4194304);    // [512][2048]
    float*          biasqkv= (float*)(ws + 6291456);             // [1536]
    unsigned short* hbuf   = (unsigned short*)(ws + 6297600);    // [8192][512] bf16 (h / h2)
    unsigned short* qkv    = (unsigned short*)(ws + 14686208);   // [8192][1536] bf16
    unsigned short* o_attn = (unsigned short*)(ws + 39852032);   // [8192][512] bf16
    unsigned short* ff1    = (unsigned short*)(ws + 48240640);   // [8192][2048] bf16

    dim3 tb(32, 8);
    transpose_cast<<<dim3(16, 16), tb, 0, stream>>>(wq, wqkvT, 512, 512);
    transpose_cast<<<dim3(16, 16), tb, 0, stream>>>(wk, wqkvT + 512 * 512, 512, 512);
    transpose_cast<<<dim3(16, 16), tb, 0, stream>>>(wv, wqkvT + 1024 * 512, 512, 512);
    transpose_cast<<<dim3(16, 16), tb, 0, stream>>>(wo, woT, 512, 512);
    transpose_cast<<<dim3(64, 16), tb, 0, stream>>>(w1, w1T, 512, 2048);
    transpose_cast<<<dim3(16, 64), tb, 0, stream>>>(w2, w2T, 2048, 512);
    concat3<<<6, 256, 0, stream>>>(bq, bk, bv, biasqkv);

    // h = LN1(x)
    ln_kernel<<<2048, 256, 0, stream>>>(x, ln1_w, ln1_b, hbuf);
    // qkv = h @ [wq|wk|wv] + [bq|bk|bv]
    gemm128<0><<<dim3(12, 64), 256, 0, stream>>>(hbuf, wqkvT, biasqkv, qkv, nullptr, 8192, 1536, 512);
    // o_attn = attention(q,k,v, bias)
    attn_kernel<<<dim3(32, 8, 4), 256, 0, stream>>>(qkv, abias, o_attn);
    // out(x2) = x + o_attn @ wo + bo
    gemm128<1><<<dim3(4, 64), 256, 0, stream>>>(o_attn, woT, bo, out, x, 8192, 512, 512);
    // h2 = LN2(x2)
    ln_kernel<<<2048, 256, 0, stream>>>(out, ln2_w, ln2_b, hbuf);
    // ff1 = GELU(h2 @ w1 + b1)
    gemm128<2><<<dim3(16, 64), 256, 0, stream>>>(hbuf, w1T, b1, ff1, nullptr, 8192, 2048, 512);
    // out = x2 + ff1 @ w2 + b2
    gemm128<3><<<dim3(4, 64), 256, 0, stream>>>(ff1, w2T, b2, out, nullptr, 8192, 512, 2048);
}

// Round 3
// 494.940 us; speedup vs baseline: 1.6518x; 1.0470x over previous
//
#include <hip/hip_runtime.h>
#include <hip/hip_bf16.h>

typedef __bf16 bf16x8 __attribute__((ext_vector_type(8)));
typedef float  f32x4  __attribute__((ext_vector_type(4)));
typedef unsigned short us8 __attribute__((ext_vector_type(8)));

__device__ inline unsigned short f2bf(float f) {
    unsigned u = __builtin_bit_cast(unsigned, f);
    u += 0x7fffu + ((u >> 16) & 1u);
    return (unsigned short)(u >> 16);
}

__device__ inline bf16x8 load_frag(const unsigned short* p) {
    return *reinterpret_cast<const bf16x8*>(p);
}

// async global->LDS, 16 bytes per lane (wave-uniform LDS base + lane*16)
__device__ inline void gload_lds16(const unsigned short* g, unsigned short* l) {
    __builtin_amdgcn_global_load_lds(
        (const __attribute__((address_space(1))) void*)g,
        (__attribute__((address_space(3))) void*)l, 16, 0, 0);
}

// ---------------- fused prep: 6 weight transposes + qkv bias concat ----------------
// blocks 0..3071: 32x32 transpose tiles; 3072..3077: bias concat
__global__ void prep_kernel(const float* __restrict__ wq, const float* __restrict__ wk,
                            const float* __restrict__ wv, const float* __restrict__ wo,
                            const float* __restrict__ w1, const float* __restrict__ w2,
                            const float* __restrict__ bq, const float* __restrict__ bk,
                            const float* __restrict__ bv,
                            unsigned short* __restrict__ wqkvT, unsigned short* __restrict__ woT,
                            unsigned short* __restrict__ w1T, unsigned short* __restrict__ w2T,
                            float* __restrict__ biasqkv) {
    int bid = blockIdx.x;
    int tx = threadIdx.x, ty = threadIdx.y;  // (32, 8)
    if (bid >= 3072) {
        int i = (bid - 3072) * 256 + ty * 32 + tx;  // 0..1535
        float v = (i < 512) ? bq[i] : ((i < 1024) ? bk[i - 512] : bv[i - 1024]);
        biasqkv[i] = v;
        return;
    }
    const float* src; unsigned short* dst; int K, N, tile;
    if (bid < 256)       { src = wq; dst = wqkvT;          K = 512;  N = 512;  tile = bid; }
    else if (bid < 512)  { src = wk; dst = wqkvT + 262144; K = 512;  N = 512;  tile = bid - 256; }
    else if (bid < 768)  { src = wv; dst = wqkvT + 524288; K = 512;  N = 512;  tile = bid - 512; }
    else if (bid < 1024) { src = wo; dst = woT;            K = 512;  N = 512;  tile = bid - 768; }
    else if (bid < 2048) { src = w1; dst = w1T;            K = 512;  N = 2048; tile = bid - 1024; }
    else                 { src = w2; dst = w2T;            K = 2048; N = 512;  tile = bid - 2048; }
    int ntx = N >> 5;
    int n0 = (tile % ntx) * 32, k0 = (tile / ntx) * 32;
    __shared__ float tilebuf[32][33];
#pragma unroll
    for (int i = 0; i < 4; ++i)
        tilebuf[ty + 8 * i][tx] = src[(size_t)(k0 + ty + 8 * i) * N + n0 + tx];
    __syncthreads();
#pragma unroll
    for (int i = 0; i < 4; ++i)
        dst[(size_t)(n0 + ty + 8 * i) * K + k0 + tx] = f2bf(tilebuf[tx][ty + 8 * i]);
}

// ---------------- LayerNorm: fp32 [R][512] -> bf16 [R][512], 1 wave per row ----------------
__global__ __launch_bounds__(256) void ln_kernel(const float* __restrict__ x,
                                                 const float* __restrict__ w,
                                                 const float* __restrict__ b,
                                                 unsigned short* __restrict__ out) {
    int wave = threadIdx.x >> 6, lane = threadIdx.x & 63;
    size_t row = (size_t)blockIdx.x * 4 + wave;
    const float* xp = x + row * 512 + lane * 8;
    float4 v0 = *reinterpret_cast<const float4*>(xp);
    float4 v1 = *reinterpret_cast<const float4*>(xp + 4);
    float s = (v0.x + v0.y) + (v0.z + v0.w) + (v1.x + v1.y) + (v1.z + v1.w);
    float qq = v0.x * v0.x + v0.y * v0.y + v0.z * v0.z + v0.w * v0.w
             + v1.x * v1.x + v1.y * v1.y + v1.z * v1.z + v1.w * v1.w;
#pragma unroll
    for (int off = 1; off < 64; off <<= 1) {
        s += __shfl_xor(s, off, 64);
        qq += __shfl_xor(qq, off, 64);
    }
    float mu = s * (1.0f / 512.0f);
    float var = qq * (1.0f / 512.0f) - mu * mu;
    float rstd = rsqrtf(var + 1e-5f);
    int c = lane * 8;
    float4 w0 = *reinterpret_cast<const float4*>(w + c);
    float4 w1 = *reinterpret_cast<const float4*>(w + c + 4);
    float4 b0 = *reinterpret_cast<const float4*>(b + c);
    float4 b1 = *reinterpret_cast<const float4*>(b + c + 4);
    us8 r;
    r[0] = f2bf((v0.x - mu) * rstd * w0.x + b0.x);
    r[1] = f2bf((v0.y - mu) * rstd * w0.y + b0.y);
    r[2] = f2bf((v0.z - mu) * rstd * w0.z + b0.z);
    r[3] = f2bf((v0.w - mu) * rstd * w0.w + b0.w);
    r[4] = f2bf((v1.x - mu) * rstd * w1.x + b1.x);
    r[5] = f2bf((v1.y - mu) * rstd * w1.y + b1.y);
    r[6] = f2bf((v1.z - mu) * rstd * w1.z + b1.z);
    r[7] = f2bf((v1.w - mu) * rstd * w1.w + b1.w);
    *reinterpret_cast<us8*>(out + row * 512 + c) = r;
}

// ---------------- m97-style 128x128 MFMA GEMM: C[M][N] = A[M][K] * BT[N][K]^T + bias --------
// EPI 0: bf16 store            (QKV)
// EPI 1: fp32 store = val+res  (x2 = x + o@wo + bo)
// EPI 2: bf16 store = GELU     (FF1)
template <int EPI>
__global__ __launch_bounds__(256) void gemm128(const unsigned short* __restrict__ A,
                                               const unsigned short* __restrict__ BT,
                                               const float* __restrict__ bias, void* Cout,
                                               const float* __restrict__ res, int M, int N, int K) {
    __shared__ unsigned short As[128 * 32];
    __shared__ unsigned short Bs[128 * 32];
    int tid = threadIdx.x;
    int lane = tid & 63, wave = tid >> 6;
    int quad = lane >> 4, l16 = lane & 15;
    int wm = (wave >> 1) * 64, wn = (wave & 1) * 64;
    int m0 = blockIdx.y * 128, n0 = blockIdx.x * 128;

    int c0 = tid, c1 = tid + 256;
    const unsigned short* ag0 = A + (size_t)(m0 + (c0 >> 2)) * K + (c0 & 3) * 8;
    const unsigned short* ag1 = A + (size_t)(m0 + (c1 >> 2)) * K + (c1 & 3) * 8;
    const unsigned short* bg0 = BT + (size_t)(n0 + (c0 >> 2)) * K + (c0 & 3) * 8;
    const unsigned short* bg1 = BT + (size_t)(n0 + (c1 >> 2)) * K + (c1 & 3) * 8;
    unsigned short* al0 = As + c0 * 8;
    unsigned short* al1 = As + c1 * 8;
    unsigned short* bl0 = Bs + c0 * 8;
    unsigned short* bl1 = Bs + c1 * 8;

    f32x4 acc[4][4] = {};
    for (int k0 = 0; k0 < K; k0 += 32) {
        __syncthreads();
        gload_lds16(ag0 + k0, al0);
        gload_lds16(ag1 + k0, al1);
        gload_lds16(bg0 + k0, bl0);
        gload_lds16(bg1 + k0, bl1);
        __syncthreads();
        bf16x8 af[4], bf[4];
#pragma unroll
        for (int i = 0; i < 4; ++i)
            af[i] = load_frag(As + (wm + i * 16 + l16) * 32 + quad * 8);
#pragma unroll
        for (int j = 0; j < 4; ++j)
            bf[j] = load_frag(Bs + (wn + j * 16 + l16) * 32 + quad * 8);
#pragma unroll
        for (int i = 0; i < 4; ++i)
#pragma unroll
            for (int j = 0; j < 4; ++j)
                acc[i][j] = __builtin_amdgcn_mfma_f32_16x16x32_bf16(af[i], bf[j], acc[i][j], 0, 0, 0);
    }

#pragma unroll
    for (int i = 0; i < 4; ++i) {
#pragma unroll
        for (int j = 0; j < 4; ++j) {
#pragma unroll
            for (int r = 0; r < 4; ++r) {
                int m = m0 + wm + i * 16 + quad * 4 + r;
                int n = n0 + wn + j * 16 + l16;
                float val = acc[i][j][r] + bias[n];
                size_t idx = (size_t)m * N + n;
                if (EPI == 0) {
                    ((unsigned short*)Cout)[idx] = f2bf(val);
                } else if (EPI == 1) {
                    ((float*)Cout)[idx] = val + res[idx];
                } else {
                    float g = 0.5f * val * (1.0f + erff(val * 0.70710678118654752f));
                    ((unsigned short*)Cout)[idx] = f2bf(g);
                }
            }
        }
    }
}

// ---------------- FF2 GEMM, split-K=2, atomicAdd into C (C pre-holds x2) ----------------
__global__ __launch_bounds__(256) void gemm128_ff2(const unsigned short* __restrict__ A,
                                                   const unsigned short* __restrict__ BT,
                                                   const float* __restrict__ bias,
                                                   float* __restrict__ C, int M, int N, int K) {
    __shared__ unsigned short As[128 * 32];
    __shared__ unsigned short Bs[128 * 32];
    int tid = threadIdx.x;
    int lane = tid & 63, wave = tid >> 6;
    int quad = lane >> 4, l16 = lane & 15;
    int wm = (wave >> 1) * 64, wn = (wave & 1) * 64;
    int m0 = blockIdx.y * 128, n0 = blockIdx.x * 128;
    int kbeg = blockIdx.z * (K >> 1), kend = kbeg + (K >> 1);

    int c0 = tid, c1 = tid + 256;
    const unsigned short* ag0 = A + (size_t)(m0 + (c0 >> 2)) * K + (c0 & 3) * 8;
    const unsigned short* ag1 = A + (size_t)(m0 + (c1 >> 2)) * K + (c1 & 3) * 8;
    const unsigned short* bg0 = BT + (size_t)(n0 + (c0 >> 2)) * K + (c0 & 3) * 8;
    const unsigned short* bg1 = BT + (size_t)(n0 + (c1 >> 2)) * K + (c1 & 3) * 8;
    unsigned short* al0 = As + c0 * 8;
    unsigned short* al1 = As + c1 * 8;
    unsigned short* bl0 = Bs + c0 * 8;
    unsigned short* bl1 = Bs + c1 * 8;

    f32x4 acc[4][4] = {};
    for (int k0 = kbeg; k0 < kend; k0 += 32) {
        __syncthreads();
        gload_lds16(ag0 + k0, al0);
        gload_lds16(ag1 + k0, al1);
        gload_lds16(bg0 + k0, bl0);
        gload_lds16(bg1 + k0, bl1);
        __syncthreads();
        bf16x8 af[4], bf[4];
#pragma unroll
        for (int i = 0; i < 4; ++i)
            af[i] = load_frag(As + (wm + i * 16 + l16) * 32 + quad * 8);
#pragma unroll
        for (int j = 0; j < 4; ++j)
            bf[j] = load_frag(Bs + (wn + j * 16 + l16) * 32 + quad * 8);
#pragma unroll
        for (int i = 0; i < 4; ++i)
#pragma unroll
            for (int j = 0; j < 4; ++j)
                acc[i][j] = __builtin_amdgcn_mfma_f32_16x16x32_bf16(af[i], bf[j], acc[i][j], 0, 0, 0);
    }

#pragma unroll
    for (int i = 0; i < 4; ++i) {
#pragma unroll
        for (int j = 0; j < 4; ++j) {
#pragma unroll
            for (int r = 0; r < 4; ++r) {
                int m = m0 + wm + i * 16 + quad * 4 + r;
                int n = n0 + wn + j * 16 + l16;
                float val = acc[i][j][r] + (blockIdx.z == 0 ? bias[n] : 0.0f);
                atomicAdd(&C[(size_t)m * N + n], val);
            }
        }
    }
}

// ---------------- flash attention, fixed-shift softmax + swizzled LDS ----------------
// One WG = (b, h, 64 q-rows); 4 waves, each 16 q-rows. K staged via glds with XOR-swizzled
// source cols; V^T and P staged with XOR chunk swizzle -> conflict-free scalar writes.
__global__ __launch_bounds__(256) void attn_kernel(const unsigned short* __restrict__ qkv,
                                                   const float* __restrict__ bias,
                                                   unsigned short* __restrict__ o) {
    __shared__ unsigned short Ks[64 * 64];   // [krow][d] chunk-swizzled: c_phys = c ^ (row&7)
    __shared__ unsigned short VTs[64 * 72];  // [d][k] stride 72, c_phys = (k>>3) ^ ((d>>4)<<1)
    __shared__ unsigned short Ps[4 * 16 * 64]; // per-wave [m][k] stride 64, c_phys = (k>>3) ^ ((m>>2)<<1)
    const int tid = threadIdx.x;
    const int lane = tid & 63, wave = tid >> 6, quad = lane >> 4, l16 = lane & 15;
    const int qb = blockIdx.x, h = blockIdx.y, b = blockIdx.z;
    const int qw = qb * 64 + wave * 16;

    const unsigned short* qbase = qkv + ((size_t)(b * 2048 + qw + l16)) * 1536 + h * 64 + quad * 8;
    bf16x8 qf0 = load_frag(qbase);
    bf16x8 qf1 = load_frag(qbase + 32);

    f32x4 Oacc[4] = {};
    float lsum[4] = {};

    // K staging (glds): wave covers rows wave*16..+15 in 2 instructions of 8 rows
    const int krow0 = wave * 16 + (lane >> 3);
    const int kc_phys = lane & 7;
    unsigned short* kl = Ks + krow0 * 64 + kc_phys * 8;  // + 8*64 for second instr
    const int ksw = (kc_phys ^ (krow0 & 7)) << 3;        // swizzled source col offset (elements)

    // V^T staging: thread loads V row srow cols sd0..sd0+15, writes column srow
    const int srow = tid >> 2, q4 = tid & 3, sd0 = q4 * 16;
    const int vt_c = (srow >> 3) ^ (q4 << 1);
    unsigned short* vtw = VTs + sd0 * 72 + vt_c * 8 + (srow & 7);

    const float* brow = bias + (size_t)h * 2048 * 2048 + (size_t)(qw + quad * 4) * 2048 + l16;

    const float S2 = 0.18033688011112042f;   // 0.125 * log2(e)
    const float K2 = 1.4426950408889634f;
    const float C2 = -11.541560327111707f;   // -8 * log2(e)

    // prefetch tile 0
    uint4 vt0, vt1;
    float bbf[4][4];
    {
        const unsigned short* kg = qkv + ((size_t)(b * 2048 + krow0)) * 1536 + 512 + h * 64 + ksw;
        gload_lds16(kg, kl);
        gload_lds16(kg + (size_t)8 * 1536, kl + 8 * 64);
        const unsigned short* vg = qkv + ((size_t)(b * 2048 + srow)) * 1536 + 1024 + h * 64 + sd0;
        vt0 = *reinterpret_cast<const uint4*>(vg);
        vt1 = *reinterpret_cast<const uint4*>(vg + 8);
#pragma unroll
        for (int t = 0; t < 4; ++t)
#pragma unroll
            for (int r = 0; r < 4; ++r)
                bbf[t][r] = fmaf(brow[(size_t)r * 2048 + t * 16], K2, C2);
    }

    for (int kt = 0; kt < 32; ++kt) {
        __syncthreads();  // prev PV done reading VTs/Ps
        {
            unsigned short vtmp[16];
            *reinterpret_cast<uint4*>(vtmp) = vt0;
            *reinterpret_cast<uint4*>(vtmp + 8) = vt1;
#pragma unroll
            for (int j = 0; j < 16; ++j) vtw[j * 72] = vtmp[j];
        }
        __syncthreads();  // staging visible (glds K drained by barrier)

        // S = Q K^T, exp, P write
#pragma unroll
        for (int t = 0; t < 4; ++t) {
            f32x4 c = {};
            bf16x8 b0 = load_frag(Ks + (t * 16 + l16) * 64 + ((quad ^ (l16 & 7)) << 3));
            bf16x8 b1 = load_frag(Ks + (t * 16 + l16) * 64 + (((quad + 4) ^ (l16 & 7)) << 3));
            c = __builtin_amdgcn_mfma_f32_16x16x32_bf16(qf0, b0, c, 0, 0, 0);
            c = __builtin_amdgcn_mfma_f32_16x16x32_bf16(qf1, b1, c, 0, 0, 0);
            int pc = (t * 2 + (l16 >> 3)) ^ (quad * 2);
            unsigned short* pw = Ps + wave * 1024 + quad * 256 + pc * 8 + (l16 & 7);
#pragma unroll
            for (int r = 0; r < 4; ++r) {
                float e = __builtin_amdgcn_exp2f(fmaf(c[r], S2, bbf[t][r]));
                lsum[r] += e;
                pw[r * 64] = f2bf(e);
            }
        }
        __syncthreads();  // P visible; Ks free

        // prefetch next tile (overlaps PV)
        {
            int kb2 = (kt < 31 ? kt + 1 : 31) * 64;
            const unsigned short* kg = qkv + ((size_t)(b * 2048 + kb2 + krow0)) * 1536 + 512 + h * 64 + ksw;
            gload_lds16(kg, kl);
            gload_lds16(kg + (size_t)8 * 1536, kl + 8 * 64);
            const unsigned short* vg = qkv + ((size_t)(b * 2048 + kb2 + srow)) * 1536 + 1024 + h * 64 + sd0;
            vt0 = *reinterpret_cast<const uint4*>(vg);
            vt1 = *reinterpret_cast<const uint4*>(vg + 8);
#pragma unroll
            for (int t = 0; t < 4; ++t)
#pragma unroll
                for (int r = 0; r < 4; ++r)
                    bbf[t][r] = fmaf(brow[(size_t)r * 2048 + kb2 + t * 16], K2, C2);
        }

        // O += P V
        bf16x8 pa0 = load_frag(Ps + wave * 1024 + l16 * 64 + ((quad ^ ((l16 >> 2) << 1)) << 3));
        bf16x8 pa1 = load_frag(Ps + wave * 1024 + l16 * 64 + (((quad + 4) ^ ((l16 >> 2) << 1)) << 3));
#pragma unroll
        for (int t = 0; t < 4; ++t) {
            bf16x8 vb0 = load_frag(VTs + (t * 16 + l16) * 72 + ((quad ^ (t * 2)) << 3));
            bf16x8 vb1 = load_frag(VTs + (t * 16 + l16) * 72 + (((quad + 4) ^ (t * 2)) << 3));
            Oacc[t] = __builtin_amdgcn_mfma_f32_16x16x32_bf16(pa0, vb0, Oacc[t], 0, 0, 0);
            Oacc[t] = __builtin_amdgcn_mfma_f32_16x16x32_bf16(pa1, vb1, Oacc[t], 0, 0, 0);
        }
    }

    // reduce row sums over the 16 k-lanes, then store O / l
#pragma unroll
    for (int off = 1; off < 16; off <<= 1)
#pragma unroll
        for (int r = 0; r < 4; ++r) lsum[r] += __shfl_xor(lsum[r], off, 64);
#pragma unroll
    for (int r = 0; r < 4; ++r) {
        float inv = 1.0f / lsum[r];
        int qg = qw + quad * 4 + r;
        unsigned short* op = o + ((size_t)(b * 2048 + qg)) * 512 + h * 64;
#pragma unroll
        for (int t = 0; t < 4; ++t) op[t * 16 + l16] = f2bf(Oacc[t][r] * inv);
    }
}

extern "C" void kernel_launch(void* const* d_in, const int* in_sizes, int n_in,
                              void* d_out, int out_size, void* d_ws, size_t ws_size,
                              hipStream_t stream) {
    const float* x      = (const float*)d_in[0];
    const float* abias  = (const float*)d_in[1];
    const float* ln1_w  = (const float*)d_in[2];
    const float* ln1_b  = (const float*)d_in[3];
    const float* ln2_w  = (const float*)d_in[4];
    const float* ln2_b  = (const float*)d_in[5];
    const float* wq     = (const float*)d_in[6];
    const float* bq     = (const float*)d_in[7];
    const float* wk     = (const float*)d_in[8];
    const float* bk     = (const float*)d_in[9];
    const float* wv     = (const float*)d_in[10];
    const float* bv     = (const float*)d_in[11];
    const float* wo     = (const float*)d_in[12];
    const float* bo     = (const float*)d_in[13];
    const float* w1     = (const float*)d_in[14];
    const float* b1     = (const float*)d_in[15];
    const float* w2     = (const float*)d_in[16];
    const float* b2     = (const float*)d_in[17];
    float* out = (float*)d_out;

    char* ws = (char*)d_ws;
    unsigned short* wqkvT  = (unsigned short*)(ws + 0);          // [1536][512] bf16
    unsigned short* woT    = (unsigned short*)(ws + 1572864);    // [512][512]
    unsigned short* w1T    = (unsigned short*)(ws + 2097152);    // [2048][512]
    unsigned short* w2T    = (unsigned short*)(ws + 4194304);    // [512][2048]
    float*          biasqkv= (float*)(ws + 6291456);             // [1536]
    unsigned short* hbuf   = (unsigned short*)(ws + 6297600);    // [8192][512] bf16 (h / h2)
    unsigned short* qkv    = (unsigned short*)(ws + 14686208);   // [8192][1536] bf16
    unsigned short* o_attn = (unsigned short*)(ws + 39852032);   // [8192][512] bf16
    unsigned short* ff1    = (unsigned short*)(ws + 48240640);   // [8192][2048] bf16

    // prep: all weight transposes + bias concat in one launch
    prep_kernel<<<3078, dim3(32, 8), 0, stream>>>(wq, wk, wv, wo, w1, w2, bq, bk, bv,
                                                  wqkvT, woT, w1T, w2T, biasqkv);
    // h = LN1(x)
    ln_kernel<<<2048, 256, 0, stream>>>(x, ln1_w, ln1_b, hbuf);
    // qkv = h @ [wq|wk|wv] + [bq|bk|bv]
    gemm128<0><<<dim3(12, 64), 256, 0, stream>>>(hbuf, wqkvT, biasqkv, qkv, nullptr, 8192, 1536, 512);
    // o_attn = attention(q,k,v, bias)
    attn_kernel<<<dim3(32, 8, 4), 256, 0, stream>>>(qkv, abias, o_attn);
    // out(x2) = x + o_attn @ wo + bo
    gemm128<1><<<dim3(4, 64), 256, 0, stream>>>(o_attn, woT, bo, out, x, 8192, 512, 512);
    // h2 = LN2(x2)
    ln_kernel<<<2048, 256, 0, stream>>>(out, ln2_w, ln2_b, hbuf);
    // ff1 = GELU(h2 @ w1 + b1)
    gemm128<2><<<dim3(16, 64), 256, 0, stream>>>(hbuf, w1T, b1, ff1, nullptr, 8192, 2048, 512);
    // out = x2 + ff1 @ w2 + b2 (split-K=2, atomic accumulate into out which holds x2)
    gemm128_ff2<<<dim3(4, 64, 2), 256, 0, stream>>>(ff1, w2T, b2, out, 8192, 512, 2048);
}

// Round 4
// 426.654 us; speedup vs baseline: 1.9161x; 1.1601x over previous
//
#include <hip/hip_runtime.h>
#include <hip/hip_bf16.h>

typedef __bf16 bf16x8 __attribute__((ext_vector_type(8)));
typedef float  f32x4  __attribute__((ext_vector_type(4)));
typedef unsigned short us8 __attribute__((ext_vector_type(8)));

__device__ inline unsigned short f2bf(float f) {
    unsigned u = __builtin_bit_cast(unsigned, f);
    u += 0x7fffu + ((u >> 16) & 1u);
    return (unsigned short)(u >> 16);
}

__device__ inline bf16x8 load_frag(const unsigned short* p) {
    return *reinterpret_cast<const bf16x8*>(p);
}

// async global->LDS, 16 bytes per lane (wave-uniform LDS base + lane*16)
__device__ inline void gload_lds16(const unsigned short* g, unsigned short* l) {
    __builtin_amdgcn_global_load_lds(
        (const __attribute__((address_space(1))) void*)g,
        (__attribute__((address_space(3))) void*)l, 16, 0, 0);
}

// ---------------- fused prep: 6 weight transposes + qkv bias concat ----------------
__global__ void prep_kernel(const float* __restrict__ wq, const float* __restrict__ wk,
                            const float* __restrict__ wv, const float* __restrict__ wo,
                            const float* __restrict__ w1, const float* __restrict__ w2,
                            const float* __restrict__ bq, const float* __restrict__ bk,
                            const float* __restrict__ bv,
                            unsigned short* __restrict__ wqkvT, unsigned short* __restrict__ woT,
                            unsigned short* __restrict__ w1T, unsigned short* __restrict__ w2T,
                            float* __restrict__ biasqkv) {
    int bid = blockIdx.x;
    int tx = threadIdx.x, ty = threadIdx.y;  // (32, 8)
    if (bid >= 3072) {
        int i = (bid - 3072) * 256 + ty * 32 + tx;  // 0..1535
        float v = (i < 512) ? bq[i] : ((i < 1024) ? bk[i - 512] : bv[i - 1024]);
        biasqkv[i] = v;
        return;
    }
    const float* src; unsigned short* dst; int K, N, tile;
    if (bid < 256)       { src = wq; dst = wqkvT;          K = 512;  N = 512;  tile = bid; }
    else if (bid < 512)  { src = wk; dst = wqkvT + 262144; K = 512;  N = 512;  tile = bid - 256; }
    else if (bid < 768)  { src = wv; dst = wqkvT + 524288; K = 512;  N = 512;  tile = bid - 512; }
    else if (bid < 1024) { src = wo; dst = woT;            K = 512;  N = 512;  tile = bid - 768; }
    else if (bid < 2048) { src = w1; dst = w1T;            K = 512;  N = 2048; tile = bid - 1024; }
    else                 { src = w2; dst = w2T;            K = 2048; N = 512;  tile = bid - 2048; }
    int ntx = N >> 5;
    int n0 = (tile % ntx) * 32, k0 = (tile / ntx) * 32;
    __shared__ float tilebuf[32][33];
#pragma unroll
    for (int i = 0; i < 4; ++i)
        tilebuf[ty + 8 * i][tx] = src[(size_t)(k0 + ty + 8 * i) * N + n0 + tx];
    __syncthreads();
#pragma unroll
    for (int i = 0; i < 4; ++i)
        dst[(size_t)(n0 + ty + 8 * i) * K + k0 + tx] = f2bf(tilebuf[tx][ty + 8 * i]);
}

// ---------------- LayerNorm: fp32 [R][512] -> bf16 [R][512], 1 wave per row ----------------
__global__ __launch_bounds__(256) void ln_kernel(const float* __restrict__ x,
                                                 const float* __restrict__ w,
                                                 const float* __restrict__ b,
                                                 unsigned short* __restrict__ out) {
    int wave = threadIdx.x >> 6, lane = threadIdx.x & 63;
    size_t row = (size_t)blockIdx.x * 4 + wave;
    const float* xp = x + row * 512 + lane * 8;
    float4 v0 = *reinterpret_cast<const float4*>(xp);
    float4 v1 = *reinterpret_cast<const float4*>(xp + 4);
    float s = (v0.x + v0.y) + (v0.z + v0.w) + (v1.x + v1.y) + (v1.z + v1.w);
    float qq = v0.x * v0.x + v0.y * v0.y + v0.z * v0.z + v0.w * v0.w
             + v1.x * v1.x + v1.y * v1.y + v1.z * v1.z + v1.w * v1.w;
#pragma unroll
    for (int off = 1; off < 64; off <<= 1) {
        s += __shfl_xor(s, off, 64);
        qq += __shfl_xor(qq, off, 64);
    }
    float mu = s * (1.0f / 512.0f);
    float var = qq * (1.0f / 512.0f) - mu * mu;
    float rstd = rsqrtf(var + 1e-5f);
    int c = lane * 8;
    float4 w0 = *reinterpret_cast<const float4*>(w + c);
    float4 w1 = *reinterpret_cast<const float4*>(w + c + 4);
    float4 b0 = *reinterpret_cast<const float4*>(b + c);
    float4 b1 = *reinterpret_cast<const float4*>(b + c + 4);
    us8 r;
    r[0] = f2bf((v0.x - mu) * rstd * w0.x + b0.x);
    r[1] = f2bf((v0.y - mu) * rstd * w0.y + b0.y);
    r[2] = f2bf((v0.z - mu) * rstd * w0.z + b0.z);
    r[3] = f2bf((v0.w - mu) * rstd * w0.w + b0.w);
    r[4] = f2bf((v1.x - mu) * rstd * w1.x + b1.x);
    r[5] = f2bf((v1.y - mu) * rstd * w1.y + b1.y);
    r[6] = f2bf((v1.z - mu) * rstd * w1.z + b1.z);
    r[7] = f2bf((v1.w - mu) * rstd * w1.w + b1.w);
    *reinterpret_cast<us8*>(out + row * 512 + c) = r;
}

// ---------------- shared GEMM core: 128x128 tile, BK=64, XOR-swizzled LDS ----------------
// swizzle: logical k-chunk cl of row r lives at phys slot cl ^ (r&7)  (chunk = 8 bf16 = 16 B)
// -> every ds_read_b128 is 2-way (free); staging via glds folds swizzle into source addr.
__device__ __forceinline__ void gemm_core(const unsigned short* __restrict__ A,
                                          const unsigned short* __restrict__ BT,
                                          int K, int kbeg, int ksteps,
                                          int m0, int n0, f32x4 (&acc)[4][4]) {
    __shared__ unsigned short As[8192];
    __shared__ unsigned short Bs[8192];
    const int tid = threadIdx.x;
    const int lane = tid & 63, wave = tid >> 6;
    const int quad = lane >> 4, l16 = lane & 15;
    const int wm = (wave >> 1) * 64, wn = (wave & 1) * 64;
    const int row0 = tid >> 3;
    const int jl = (tid & 7) ^ (row0 & 7);
    const unsigned short* ag = A + (size_t)(m0 + row0) * K + kbeg + jl * 8;
    const unsigned short* bg = BT + (size_t)(n0 + row0) * K + kbeg + jl * 8;
    unsigned short* al = As + tid * 8;
    unsigned short* bl = Bs + tid * 8;
    const int sw = l16 & 7;

    for (int ks = 0; ks < ksteps; ++ks) {
        __syncthreads();
#pragma unroll
        for (int s = 0; s < 4; ++s) {
            gload_lds16(ag + (size_t)32 * s * K, al + 2048 * s);
            gload_lds16(bg + (size_t)32 * s * K, bl + 2048 * s);
        }
        ag += 64; bg += 64;
        __syncthreads();
#pragma unroll
        for (int h = 0; h < 2; ++h) {
            bf16x8 af[4], bf[4];
#pragma unroll
            for (int i = 0; i < 4; ++i)
                af[i] = load_frag(As + (wm + i * 16 + l16) * 64 + (((h * 4 + quad) ^ sw) * 8));
#pragma unroll
            for (int j = 0; j < 4; ++j)
                bf[j] = load_frag(Bs + (wn + j * 16 + l16) * 64 + (((h * 4 + quad) ^ sw) * 8));
#pragma unroll
            for (int i = 0; i < 4; ++i)
#pragma unroll
                for (int j = 0; j < 4; ++j)
                    acc[i][j] = __builtin_amdgcn_mfma_f32_16x16x32_bf16(af[i], bf[j], acc[i][j], 0, 0, 0);
        }
    }
}

// QKV GEMM: writes Q,K into qk[token][1024] (bf16) and V transposed into vT[b*512+hd][2048]
__global__ __launch_bounds__(256, 3) void gemm_qkv_k(const unsigned short* __restrict__ A,
                                                     const unsigned short* __restrict__ BT,
                                                     const float* __restrict__ bias,
                                                     unsigned short* __restrict__ qk,
                                                     unsigned short* __restrict__ vT) {
    f32x4 acc[4][4] = {};
    const int m0 = blockIdx.y * 128, n0 = blockIdx.x * 128;
    gemm_core(A, BT, 512, 0, 8, m0, n0, acc);
    const int tid = threadIdx.x, lane = tid & 63, wave = tid >> 6;
    const int quad = lane >> 4, l16 = lane & 15;
    const int wm = (wave >> 1) * 64, wn = (wave & 1) * 64;
    if (n0 < 1024) {
#pragma unroll
        for (int i = 0; i < 4; ++i)
#pragma unroll
            for (int j = 0; j < 4; ++j) {
                int n = n0 + wn + j * 16 + l16;
                float bn = bias[n];
#pragma unroll
                for (int r = 0; r < 4; ++r) {
                    int m = m0 + wm + i * 16 + quad * 4 + r;
                    qk[(size_t)m * 1024 + n] = f2bf(acc[i][j][r] + bn);
                }
            }
    } else {
#pragma unroll
        for (int i = 0; i < 4; ++i) {
            int mb = m0 + wm + i * 16 + quad * 4;
            int bb = mb >> 11, tok = mb & 2047;
#pragma unroll
            for (int j = 0; j < 4; ++j) {
                int n = n0 + wn + j * 16 + l16;
                float bn = bias[n];
                int hd = n - 1024;
                ushort4 pk;
                pk.x = f2bf(acc[i][j][0] + bn);
                pk.y = f2bf(acc[i][j][1] + bn);
                pk.z = f2bf(acc[i][j][2] + bn);
                pk.w = f2bf(acc[i][j][3] + bn);
                *reinterpret_cast<ushort4*>(vT + (size_t)(bb * 512 + hd) * 2048 + tok) = pk;
            }
        }
    }
}

// FF1 GEMM: GELU epilogue, bf16 store
__global__ __launch_bounds__(256, 3) void gemm_gelu_k(const unsigned short* __restrict__ A,
                                                      const unsigned short* __restrict__ BT,
                                                      const float* __restrict__ bias,
                                                      unsigned short* __restrict__ C) {
    f32x4 acc[4][4] = {};
    const int m0 = blockIdx.y * 128, n0 = blockIdx.x * 128;
    gemm_core(A, BT, 512, 0, 8, m0, n0, acc);
    const int tid = threadIdx.x, lane = tid & 63, wave = tid >> 6;
    const int quad = lane >> 4, l16 = lane & 15;
    const int wm = (wave >> 1) * 64, wn = (wave & 1) * 64;
#pragma unroll
    for (int i = 0; i < 4; ++i)
#pragma unroll
        for (int j = 0; j < 4; ++j) {
            int n = n0 + wn + j * 16 + l16;
            float bn = bias[n];
#pragma unroll
            for (int r = 0; r < 4; ++r) {
                int m = m0 + wm + i * 16 + quad * 4 + r;
                float val = acc[i][j][r] + bn;
                float g = 0.5f * val * (1.0f + erff(val * 0.70710678118654752f));
                C[(size_t)m * 2048 + n] = f2bf(g);
            }
        }
}

// split-K GEMM: atomicAdd fp32 into C (C pre-holds residual); bias added by z==0 only
__global__ __launch_bounds__(256, 3) void gemm_atomic_k(const unsigned short* __restrict__ A,
                                                        const unsigned short* __restrict__ BT,
                                                        const float* __restrict__ bias,
                                                        float* __restrict__ C,
                                                        int N, int K, int ksteps) {
    f32x4 acc[4][4] = {};
    const int m0 = blockIdx.y * 128, n0 = blockIdx.x * 128;
    const int kbeg = blockIdx.z * ksteps * 64;
    gemm_core(A, BT, K, kbeg, ksteps, m0, n0, acc);
    const int tid = threadIdx.x, lane = tid & 63, wave = tid >> 6;
    const int quad = lane >> 4, l16 = lane & 15;
    const int wm = (wave >> 1) * 64, wn = (wave & 1) * 64;
    const bool addb = (blockIdx.z == 0);
#pragma unroll
    for (int i = 0; i < 4; ++i)
#pragma unroll
        for (int j = 0; j < 4; ++j) {
            int n = n0 + wn + j * 16 + l16;
            float bn = addb ? bias[n] : 0.0f;
#pragma unroll
            for (int r = 0; r < 4; ++r) {
                int m = m0 + wm + i * 16 + quad * 4 + r;
                atomicAdd(&C[(size_t)m * N + n], acc[i][j][r] + bn);
            }
        }
}

// ---------------- flash attention: double-buffered glds K/V^T, 2 barriers/tile ----------------
__global__ __launch_bounds__(256, 4) void attn_kernel(const unsigned short* __restrict__ qk,
                                                      const unsigned short* __restrict__ vT,
                                                      const float* __restrict__ bias,
                                                      unsigned short* __restrict__ o) {
    __shared__ unsigned short Ks[2][4096];   // [krow][d], chunk swizzle cl^(row&7)
    __shared__ unsigned short VTs[2][4096];  // [d][kt], same swizzle
    __shared__ unsigned short Ps[4096];      // per-wave [m][kt], swizzle cl^((m>>1)&7)
    const int tid = threadIdx.x;
    const int lane = tid & 63, wave = tid >> 6, quad = lane >> 4, l16 = lane & 15;
    const int qb = blockIdx.x, h = blockIdx.y, b = blockIdx.z;
    const int qw = qb * 64 + wave * 16;

    const unsigned short* qbase = qk + (size_t)(b * 2048 + qw + l16) * 1024 + h * 64 + quad * 8;
    bf16x8 qf0 = load_frag(qbase);
    bf16x8 qf1 = load_frag(qbase + 32);

    f32x4 Oacc[4] = {};
    float lsum[4] = {};

    // staging: per wave 2 glds rows-groups (r0, r0+8), phys slot = lane&7
    const int p8 = lane & 7;
    const int r0 = wave * 16 + (lane >> 3);
    const int swz = (p8 ^ (r0 & 7)) * 8;
    const unsigned short* kg = qk + (size_t)(b * 2048 + r0) * 1024 + 512 + h * 64 + swz;
    const unsigned short* vg = vT + (size_t)(b * 512 + h * 64 + r0) * 2048 + swz;
    const int ldst = r0 * 64 + p8 * 8;

    const float* brow = bias + (size_t)h * 2048 * 2048 + (size_t)(qw + quad * 4) * 2048 + l16;
    const float S2 = 0.18033688011112042f;   // 0.125 * log2(e)
    const float K2 = 1.4426950408889634f;    // log2(e)
    const float C2 = -11.541560327111707f;   // -8 * log2(e)

    // prefetch tile 0
    gload_lds16(kg, Ks[0] + ldst);
    gload_lds16(kg + 8 * 1024, Ks[0] + 512 + ldst);
    gload_lds16(vg, VTs[0] + ldst);
    gload_lds16(vg + 8 * 2048, VTs[0] + 512 + ldst);
    float bbf[4][4];
#pragma unroll
    for (int t = 0; t < 4; ++t)
#pragma unroll
        for (int r = 0; r < 4; ++r)
            bbf[t][r] = fmaf(brow[(size_t)r * 2048 + t * 16], K2, C2);

    const int sw7 = l16 & 7;
    for (int kt = 0; kt < 32; ++kt) {
        const int buf = kt & 1;
        __syncthreads();  // glds(kt) drained & visible; prev tile fully consumed
        if (kt < 31) {
            const unsigned short* kg2 = kg + (size_t)(kt + 1) * 64 * 1024;
            const unsigned short* vg2 = vg + (kt + 1) * 64;
            gload_lds16(kg2, Ks[buf ^ 1] + ldst);
            gload_lds16(kg2 + 8 * 1024, Ks[buf ^ 1] + 512 + ldst);
            gload_lds16(vg2, VTs[buf ^ 1] + ldst);
            gload_lds16(vg2 + 8 * 2048, VTs[buf ^ 1] + 512 + ldst);
        }
        // S = Q K^T -> exp -> P (LDS, A-layout-ready)
#pragma unroll
        for (int t = 0; t < 4; ++t) {
            const unsigned short* krow = Ks[buf] + (t * 16 + l16) * 64;
            bf16x8 kb0 = load_frag(krow + ((quad ^ sw7) * 8));
            bf16x8 kb1 = load_frag(krow + (((quad + 4) ^ sw7) * 8));
            f32x4 c = {};
            c = __builtin_amdgcn_mfma_f32_16x16x32_bf16(qf0, kb0, c, 0, 0, 0);
            c = __builtin_amdgcn_mfma_f32_16x16x32_bf16(qf1, kb1, c, 0, 0, 0);
#pragma unroll
            for (int r = 0; r < 4; ++r) {
                float e = __builtin_amdgcn_exp2f(fmaf(c[r], S2, bbf[t][r]));
                lsum[r] += e;
                int m = quad * 4 + r;
                int phys = (t * 2 + (l16 >> 3)) ^ ((m >> 1) & 7);
                Ps[wave * 1024 + m * 64 + phys * 8 + (l16 & 7)] = f2bf(e);
            }
        }
        __syncthreads();  // P visible (also drains next-tile glds; they had the QK window)
        // prefetch next tile's bias into regs (overlaps PV)
        if (kt < 31) {
            const float* b2 = brow + (size_t)(kt + 1) * 64;
#pragma unroll
            for (int t = 0; t < 4; ++t)
#pragma unroll
                for (int r = 0; r < 4; ++r)
                    bbf[t][r] = fmaf(b2[(size_t)r * 2048 + t * 16], K2, C2);
        }
        // O += P V
        const unsigned short* prow = Ps + wave * 1024 + l16 * 64;
        bf16x8 pa0 = load_frag(prow + ((quad ^ ((l16 >> 1) & 7)) * 8));
        bf16x8 pa1 = load_frag(prow + (((quad + 4) ^ ((l16 >> 1) & 7)) * 8));
#pragma unroll
        for (int t = 0; t < 4; ++t) {
            const unsigned short* vrow = VTs[buf] + (t * 16 + l16) * 64;
            bf16x8 vb0 = load_frag(vrow + ((quad ^ sw7) * 8));
            bf16x8 vb1 = load_frag(vrow + (((quad + 4) ^ sw7) * 8));
            Oacc[t] = __builtin_amdgcn_mfma_f32_16x16x32_bf16(pa0, vb0, Oacc[t], 0, 0, 0);
            Oacc[t] = __builtin_amdgcn_mfma_f32_16x16x32_bf16(pa1, vb1, Oacc[t], 0, 0, 0);
        }
    }

    // reduce row sums over 16 k-lanes, store O / l
#pragma unroll
    for (int off = 1; off < 16; off <<= 1)
#pragma unroll
        for (int r = 0; r < 4; ++r) lsum[r] += __shfl_xor(lsum[r], off, 64);
#pragma unroll
    for (int r = 0; r < 4; ++r) {
        float inv = 1.0f / lsum[r];
        int qg = qw + quad * 4 + r;
        unsigned short* op = o + (size_t)(b * 2048 + qg) * 512 + h * 64;
#pragma unroll
        for (int t = 0; t < 4; ++t) op[t * 16 + l16] = f2bf(Oacc[t][r] * inv);
    }
}

extern "C" void kernel_launch(void* const* d_in, const int* in_sizes, int n_in,
                              void* d_out, int out_size, void* d_ws, size_t ws_size,
                              hipStream_t stream) {
    const float* x      = (const float*)d_in[0];
    const float* abias  = (const float*)d_in[1];
    const float* ln1_w  = (const float*)d_in[2];
    const float* ln1_b  = (const float*)d_in[3];
    const float* ln2_w  = (const float*)d_in[4];
    const float* ln2_b  = (const float*)d_in[5];
    const float* wq     = (const float*)d_in[6];
    const float* bq     = (const float*)d_in[7];
    const float* wk     = (const float*)d_in[8];
    const float* bk     = (const float*)d_in[9];
    const float* wv     = (const float*)d_in[10];
    const float* bv     = (const float*)d_in[11];
    const float* wo     = (const float*)d_in[12];
    const float* bo     = (const float*)d_in[13];
    const float* w1     = (const float*)d_in[14];
    const float* b1     = (const float*)d_in[15];
    const float* w2     = (const float*)d_in[16];
    const float* b2     = (const float*)d_in[17];
    float* out = (float*)d_out;

    char* ws = (char*)d_ws;
    unsigned short* wqkvT  = (unsigned short*)(ws + 0);          // [1536][512] bf16
    unsigned short* woT    = (unsigned short*)(ws + 1572864);    // [512][512]
    unsigned short* w1T    = (unsigned short*)(ws + 2097152);    // [2048][512]
    unsigned short* w2T    = (unsigned short*)(ws + 4194304);    // [512][2048]
    float*          biasqkv= (float*)(ws + 6291456);             // [1536]
    unsigned short* hbuf   = (unsigned short*)(ws + 6297600);    // [8192][512] bf16 (h / h2)
    unsigned short* qkbuf  = (unsigned short*)(ws + 14686208);   // [8192][1024] bf16 (Q|K)
    unsigned short* vTbuf  = (unsigned short*)(ws + 31463424);   // [4*512][2048] bf16 (V^T per b,h)
    unsigned short* o_attn = (unsigned short*)(ws + 39852032);   // [8192][512] bf16
    unsigned short* ff1    = (unsigned short*)(ws + 48240640);   // [8192][2048] bf16

    // out <- x (residual base for the two atomic GEMMs)
    hipMemcpyAsync(out, x, (size_t)8192 * 512 * sizeof(float), hipMemcpyDeviceToDevice, stream);
    // weights transpose/cast + bias concat
    prep_kernel<<<3078, dim3(32, 8), 0, stream>>>(wq, wk, wv, wo, w1, w2, bq, bk, bv,
                                                  wqkvT, woT, w1T, w2T, biasqkv);
    // h = LN1(x)
    ln_kernel<<<2048, 256, 0, stream>>>(x, ln1_w, ln1_b, hbuf);
    // qkbuf/vT = h @ [wq|wk|wv] + biases  (V written transposed)
    gemm_qkv_k<<<dim3(12, 64), 256, 0, stream>>>(hbuf, wqkvT, biasqkv, qkbuf, vTbuf);
    // o_attn = attention(q,k,v, bias)
    attn_kernel<<<dim3(32, 8, 4), 256, 0, stream>>>(qkbuf, vTbuf, abias, o_attn);
    // out += o_attn @ wo + bo   (split-K=2 atomic; out pre-holds x)
    gemm_atomic_k<<<dim3(4, 64, 2), 256, 0, stream>>>(o_attn, woT, bo, out, 512, 512, 4);
    // h2 = LN2(out)
    ln_kernel<<<2048, 256, 0, stream>>>(out, ln2_w, ln2_b, hbuf);
    // ff1 = GELU(h2 @ w1 + b1)
    gemm_gelu_k<<<dim3(16, 64), 256, 0, stream>>>(hbuf, w1T, b1, ff1);
    // out += ff1 @ w2 + b2   (split-K=2 atomic)
    gemm_atomic_k<<<dim3(4, 64, 2), 256, 0, stream>>>(ff1, w2T, b2, out, 512, 2048, 16);
}

// Round 5
// 416.986 us; speedup vs baseline: 1.9606x; 1.0232x over previous
//
#include <hip/hip_runtime.h>
#include <hip/hip_bf16.h>

typedef __bf16 bf16x8 __attribute__((ext_vector_type(8)));
typedef float  f32x4  __attribute__((ext_vector_type(4)));
typedef unsigned short us8 __attribute__((ext_vector_type(8)));

__device__ inline unsigned short f2bf(float f) {
    unsigned u = __builtin_bit_cast(unsigned, f);
    u += 0x7fffu + ((u >> 16) & 1u);
    return (unsigned short)(u >> 16);
}

__device__ inline bf16x8 load_frag(const unsigned short* p) {
    return *reinterpret_cast<const bf16x8*>(p);
}

// async global->LDS, 16 bytes per lane (wave-uniform LDS base + lane*16)
__device__ inline void gload_lds16(const unsigned short* g, unsigned short* l) {
    __builtin_amdgcn_global_load_lds(
        (const __attribute__((address_space(1))) void*)g,
        (__attribute__((address_space(3))) void*)l, 16, 0, 0);
}

// ---------------- fused prep: 6 weight transposes + qkv bias concat ----------------
__global__ void prep_kernel(const float* __restrict__ wq, const float* __restrict__ wk,
                            const float* __restrict__ wv, const float* __restrict__ wo,
                            const float* __restrict__ w1, const float* __restrict__ w2,
                            const float* __restrict__ bq, const float* __restrict__ bk,
                            const float* __restrict__ bv,
                            unsigned short* __restrict__ wqkvT, unsigned short* __restrict__ woT,
                            unsigned short* __restrict__ w1T, unsigned short* __restrict__ w2T,
                            float* __restrict__ biasqkv) {
    int bid = blockIdx.x;
    int tx = threadIdx.x, ty = threadIdx.y;  // (32, 8)
    if (bid >= 3072) {
        int i = (bid - 3072) * 256 + ty * 32 + tx;  // 0..1535
        float v = (i < 512) ? bq[i] : ((i < 1024) ? bk[i - 512] : bv[i - 1024]);
        biasqkv[i] = v;
        return;
    }
    const float* src; unsigned short* dst; int K, N, tile;
    if (bid < 256)       { src = wq; dst = wqkvT;          K = 512;  N = 512;  tile = bid; }
    else if (bid < 512)  { src = wk; dst = wqkvT + 262144; K = 512;  N = 512;  tile = bid - 256; }
    else if (bid < 768)  { src = wv; dst = wqkvT + 524288; K = 512;  N = 512;  tile = bid - 512; }
    else if (bid < 1024) { src = wo; dst = woT;            K = 512;  N = 512;  tile = bid - 768; }
    else if (bid < 2048) { src = w1; dst = w1T;            K = 512;  N = 2048; tile = bid - 1024; }
    else                 { src = w2; dst = w2T;            K = 2048; N = 512;  tile = bid - 2048; }
    int ntx = N >> 5;
    int n0 = (tile % ntx) * 32, k0 = (tile / ntx) * 32;
    __shared__ float tilebuf[32][33];
#pragma unroll
    for (int i = 0; i < 4; ++i)
        tilebuf[ty + 8 * i][tx] = src[(size_t)(k0 + ty + 8 * i) * N + n0 + tx];
    __syncthreads();
#pragma unroll
    for (int i = 0; i < 4; ++i)
        dst[(size_t)(n0 + ty + 8 * i) * K + k0 + tx] = f2bf(tilebuf[tx][ty + 8 * i]);
}

// ---------------- LayerNorm: fp32 [R][512] -> bf16 [R][512], 1 wave per row ----------------
__global__ __launch_bounds__(256) void ln_kernel(const float* __restrict__ x,
                                                 const float* __restrict__ w,
                                                 const float* __restrict__ b,
                                                 unsigned short* __restrict__ out) {
    int wave = threadIdx.x >> 6, lane = threadIdx.x & 63;
    size_t row = (size_t)blockIdx.x * 4 + wave;
    const float* xp = x + row * 512 + lane * 8;
    float4 v0 = *reinterpret_cast<const float4*>(xp);
    float4 v1 = *reinterpret_cast<const float4*>(xp + 4);
    float s = (v0.x + v0.y) + (v0.z + v0.w) + (v1.x + v1.y) + (v1.z + v1.w);
    float qq = v0.x * v0.x + v0.y * v0.y + v0.z * v0.z + v0.w * v0.w
             + v1.x * v1.x + v1.y * v1.y + v1.z * v1.z + v1.w * v1.w;
#pragma unroll
    for (int off = 1; off < 64; off <<= 1) {
        s += __shfl_xor(s, off, 64);
        qq += __shfl_xor(qq, off, 64);
    }
    float mu = s * (1.0f / 512.0f);
    float var = qq * (1.0f / 512.0f) - mu * mu;
    float rstd = rsqrtf(var + 1e-5f);
    int c = lane * 8;
    float4 w0 = *reinterpret_cast<const float4*>(w + c);
    float4 w1 = *reinterpret_cast<const float4*>(w + c + 4);
    float4 b0 = *reinterpret_cast<const float4*>(b + c);
    float4 b1 = *reinterpret_cast<const float4*>(b + c + 4);
    us8 r;
    r[0] = f2bf((v0.x - mu) * rstd * w0.x + b0.x);
    r[1] = f2bf((v0.y - mu) * rstd * w0.y + b0.y);
    r[2] = f2bf((v0.z - mu) * rstd * w0.z + b0.z);
    r[3] = f2bf((v0.w - mu) * rstd * w0.w + b0.w);
    r[4] = f2bf((v1.x - mu) * rstd * w1.x + b1.x);
    r[5] = f2bf((v1.y - mu) * rstd * w1.y + b1.y);
    r[6] = f2bf((v1.z - mu) * rstd * w1.z + b1.z);
    r[7] = f2bf((v1.w - mu) * rstd * w1.w + b1.w);
    *reinterpret_cast<us8*>(out + row * 512 + c) = r;
}

// ---------------- GEMM core 128x128, BK=64, XOR-swizzled LDS (2-way reads, free) -------------
__device__ __forceinline__ void gemm_core(const unsigned short* __restrict__ A,
                                          const unsigned short* __restrict__ BT,
                                          int K, int ksteps,
                                          int m0, int n0, f32x4 (&acc)[4][4]) {
    __shared__ unsigned short As[8192];
    __shared__ unsigned short Bs[8192];
    const int tid = threadIdx.x;
    const int lane = tid & 63, wave = tid >> 6;
    const int quad = lane >> 4, l16 = lane & 15;
    const int wm = (wave >> 1) * 64, wn = (wave & 1) * 64;
    const int row0 = tid >> 3;
    const int jl = (tid & 7) ^ (row0 & 7);
    const unsigned short* ag = A + (size_t)(m0 + row0) * K + jl * 8;
    const unsigned short* bg = BT + (size_t)(n0 + row0) * K + jl * 8;
    unsigned short* al = As + tid * 8;
    unsigned short* bl = Bs + tid * 8;
    const int sw = l16 & 7;

    for (int ks = 0; ks < ksteps; ++ks) {
        __syncthreads();
#pragma unroll
        for (int s = 0; s < 4; ++s) {
            gload_lds16(ag + (size_t)32 * s * K, al + 2048 * s);
            gload_lds16(bg + (size_t)32 * s * K, bl + 2048 * s);
        }
        ag += 64; bg += 64;
        __syncthreads();
#pragma unroll
        for (int h = 0; h < 2; ++h) {
            bf16x8 af[4], bf[4];
#pragma unroll
            for (int i = 0; i < 4; ++i)
                af[i] = load_frag(As + (wm + i * 16 + l16) * 64 + (((h * 4 + quad) ^ sw) * 8));
#pragma unroll
            for (int j = 0; j < 4; ++j)
                bf[j] = load_frag(Bs + (wn + j * 16 + l16) * 64 + (((h * 4 + quad) ^ sw) * 8));
#pragma unroll
            for (int i = 0; i < 4; ++i)
#pragma unroll
                for (int j = 0; j < 4; ++j)
                    acc[i][j] = __builtin_amdgcn_mfma_f32_16x16x32_bf16(af[i], bf[j], acc[i][j], 0, 0, 0);
        }
    }
}

// ---------------- GEMM core 128(M)x64(N), BK=64, same swizzle ----------------
__device__ __forceinline__ void gemm_core_n64(const unsigned short* __restrict__ A,
                                              const unsigned short* __restrict__ BT,
                                              int K, int ksteps,
                                              int m0, int n0, f32x4 (&acc)[2][4]) {
    __shared__ unsigned short As[8192];
    __shared__ unsigned short Bs[4096];
    const int tid = threadIdx.x;
    const int lane = tid & 63, wave = tid >> 6;
    const int quad = lane >> 4, l16 = lane & 15;
    const int wm = wave * 32;
    const int row0 = tid >> 3;
    const int jl = (tid & 7) ^ (row0 & 7);
    const unsigned short* ag = A + (size_t)(m0 + row0) * K + jl * 8;
    const unsigned short* bg = BT + (size_t)(n0 + (row0 & 31)) * K + jl * 8;  // rows 0..31 (+32 via s)
    unsigned short* al = As + tid * 8;
    unsigned short* bl = Bs + tid * 8;
    const bool bstage = (row0 < 32);  // first 256 chunks... (tid<256 always true; s loop below)
    (void)bstage;
    const int sw = l16 & 7;

    for (int ks = 0; ks < ksteps; ++ks) {
        __syncthreads();
#pragma unroll
        for (int s = 0; s < 4; ++s)
            gload_lds16(ag + (size_t)32 * s * K, al + 2048 * s);
#pragma unroll
        for (int s = 0; s < 2; ++s)
            gload_lds16(bg + (size_t)32 * s * K, bl + 2048 * s);
        ag += 64; bg += 64;
        __syncthreads();
#pragma unroll
        for (int h = 0; h < 2; ++h) {
            bf16x8 af[2], bf[4];
#pragma unroll
            for (int i = 0; i < 2; ++i)
                af[i] = load_frag(As + (wm + i * 16 + l16) * 64 + (((h * 4 + quad) ^ sw) * 8));
#pragma unroll
            for (int j = 0; j < 4; ++j)
                bf[j] = load_frag(Bs + (j * 16 + l16) * 64 + (((h * 4 + quad) ^ sw) * 8));
#pragma unroll
            for (int i = 0; i < 2; ++i)
#pragma unroll
                for (int j = 0; j < 4; ++j)
                    acc[i][j] = __builtin_amdgcn_mfma_f32_16x16x32_bf16(af[i], bf[j], acc[i][j], 0, 0, 0);
        }
    }
}

// Bs staging note: tid 0..255 covers c = tid (row=tid>>3 in 0..31) and c+256 (row+32).
// bg uses (row0 & 31): for tid>=256 impossible; s=1 adds +32 rows via pointer offset below.
// (bg second gload offset handled by 32*s*K with row0<32: rows row0 and row0+32.)

// O-proj GEMM: out = x + A@woT + bo   (128x64 tile, no atomics)
__global__ __launch_bounds__(256) void gemm_oproj(const unsigned short* __restrict__ A,
                                                  const unsigned short* __restrict__ BT,
                                                  const float* __restrict__ bias,
                                                  const float* __restrict__ res,
                                                  float* __restrict__ C) {
    f32x4 acc[2][4] = {};
    const int m0 = blockIdx.y * 128, n0 = blockIdx.x * 64;
    gemm_core_n64(A, BT, 512, 8, m0, n0, acc);
    const int tid = threadIdx.x, lane = tid & 63, wave = tid >> 6;
    const int quad = lane >> 4, l16 = lane & 15;
    const int wm = wave * 32;
#pragma unroll
    for (int i = 0; i < 2; ++i)
#pragma unroll
        for (int j = 0; j < 4; ++j) {
            int n = n0 + j * 16 + l16;
            float bn = bias[n];
#pragma unroll
            for (int r = 0; r < 4; ++r) {
                int m = m0 + wm + i * 16 + quad * 4 + r;
                size_t idx = (size_t)m * 512 + n;
                C[idx] = acc[i][j][r] + bn + res[idx];
            }
        }
}

// FF2 GEMM: out += A@w2T + b2   (128x64 tile, K=2048, no atomics)
__global__ __launch_bounds__(256) void gemm_ff2(const unsigned short* __restrict__ A,
                                                const unsigned short* __restrict__ BT,
                                                const float* __restrict__ bias,
                                                float* __restrict__ C) {
    f32x4 acc[2][4] = {};
    const int m0 = blockIdx.y * 128, n0 = blockIdx.x * 64;
    gemm_core_n64(A, BT, 2048, 32, m0, n0, acc);
    const int tid = threadIdx.x, lane = tid & 63, wave = tid >> 6;
    const int quad = lane >> 4, l16 = lane & 15;
    const int wm = wave * 32;
#pragma unroll
    for (int i = 0; i < 2; ++i)
#pragma unroll
        for (int j = 0; j < 4; ++j) {
            int n = n0 + j * 16 + l16;
            float bn = bias[n];
#pragma unroll
            for (int r = 0; r < 4; ++r) {
                int m = m0 + wm + i * 16 + quad * 4 + r;
                size_t idx = (size_t)m * 512 + n;
                C[idx] = C[idx] + acc[i][j][r] + bn;
            }
        }
}

// QKV GEMM: writes Q,K into qk[token][1024] (bf16) and V transposed into vT[b*512+hd][2048]
__global__ __launch_bounds__(256) void gemm_qkv_k(const unsigned short* __restrict__ A,
                                                  const unsigned short* __restrict__ BT,
                                                  const float* __restrict__ bias,
                                                  unsigned short* __restrict__ qk,
                                                  unsigned short* __restrict__ vT) {
    f32x4 acc[4][4] = {};
    const int m0 = blockIdx.y * 128, n0 = blockIdx.x * 128;
    gemm_core(A, BT, 512, 8, m0, n0, acc);
    const int tid = threadIdx.x, lane = tid & 63, wave = tid >> 6;
    const int quad = lane >> 4, l16 = lane & 15;
    const int wm = (wave >> 1) * 64, wn = (wave & 1) * 64;
    if (n0 < 1024) {
#pragma unroll
        for (int i = 0; i < 4; ++i)
#pragma unroll
            for (int j = 0; j < 4; ++j) {
                int n = n0 + wn + j * 16 + l16;
                float bn = bias[n];
#pragma unroll
                for (int r = 0; r < 4; ++r) {
                    int m = m0 + wm + i * 16 + quad * 4 + r;
                    qk[(size_t)m * 1024 + n] = f2bf(acc[i][j][r] + bn);
                }
            }
    } else {
#pragma unroll
        for (int i = 0; i < 4; ++i) {
            int mb = m0 + wm + i * 16 + quad * 4;
            int bb = mb >> 11, tok = mb & 2047;
#pragma unroll
            for (int j = 0; j < 4; ++j) {
                int n = n0 + wn + j * 16 + l16;
                float bn = bias[n];
                int hd = n - 1024;
                ushort4 pk;
                pk.x = f2bf(acc[i][j][0] + bn);
                pk.y = f2bf(acc[i][j][1] + bn);
                pk.z = f2bf(acc[i][j][2] + bn);
                pk.w = f2bf(acc[i][j][3] + bn);
                *reinterpret_cast<ushort4*>(vT + (size_t)(bb * 512 + hd) * 2048 + tok) = pk;
            }
        }
    }
}

// FF1 GEMM: GELU epilogue, bf16 store
__global__ __launch_bounds__(256) void gemm_gelu_k(const unsigned short* __restrict__ A,
                                                   const unsigned short* __restrict__ BT,
                                                   const float* __restrict__ bias,
                                                   unsigned short* __restrict__ C) {
    f32x4 acc[4][4] = {};
    const int m0 = blockIdx.y * 128, n0 = blockIdx.x * 128;
    gemm_core(A, BT, 512, 8, m0, n0, acc);
    const int tid = threadIdx.x, lane = tid & 63, wave = tid >> 6;
    const int quad = lane >> 4, l16 = lane & 15;
    const int wm = (wave >> 1) * 64, wn = (wave & 1) * 64;
#pragma unroll
    for (int i = 0; i < 4; ++i)
#pragma unroll
        for (int j = 0; j < 4; ++j) {
            int n = n0 + wn + j * 16 + l16;
            float bn = bias[n];
#pragma unroll
            for (int r = 0; r < 4; ++r) {
                int m = m0 + wm + i * 16 + quad * 4 + r;
                float val = acc[i][j][r] + bn;
                float g = 0.5f * val * (1.0f + erff(val * 0.70710678118654752f));
                C[(size_t)m * 2048 + n] = f2bf(g);
            }
        }
}

// ---------------- flash attention: 2 batches per block, shared bias tile ----------------
// grid (32 qb, 8 h, 2 bp); double-buffered glds K/V^T; fixed-shift softmax; swizzled LDS.
__global__ __launch_bounds__(256) void attn_kernel(const unsigned short* __restrict__ qk,
                                                   const unsigned short* __restrict__ vT,
                                                   const float* __restrict__ bias,
                                                   unsigned short* __restrict__ o) {
    __shared__ unsigned short Ks[2][2][4096];   // [buf][batch][krow][d] chunk swizzle cl^(row&7)
    __shared__ unsigned short VTs[2][2][4096];  // [buf][batch][d][kt]
    __shared__ unsigned short Ps[2][4096];      // [batch][wave][m][kt]
    const int tid = threadIdx.x;
    const int lane = tid & 63, wave = tid >> 6, quad = lane >> 4, l16 = lane & 15;
    const int qb = blockIdx.x, h = blockIdx.y, bp = blockIdx.z;
    const int qw = qb * 64 + wave * 16;

    bf16x8 qf[2][2];
#pragma unroll
    for (int bi = 0; bi < 2; ++bi) {
        const unsigned short* qbase =
            qk + (size_t)((bp * 2 + bi) * 2048 + qw + l16) * 1024 + h * 64 + quad * 8;
        qf[bi][0] = load_frag(qbase);
        qf[bi][1] = load_frag(qbase + 32);
    }

    f32x4 Oacc[2][4] = {};
    float lsum[2][4] = {};

    const int p8 = lane & 7;
    const int r0 = wave * 16 + (lane >> 3);
    const int swz = (p8 ^ (r0 & 7)) * 8;
    const unsigned short* kg[2];
    const unsigned short* vg[2];
#pragma unroll
    for (int bi = 0; bi < 2; ++bi) {
        int b = bp * 2 + bi;
        kg[bi] = qk + (size_t)(b * 2048 + r0) * 1024 + 512 + h * 64 + swz;
        vg[bi] = vT + (size_t)(b * 512 + h * 64 + r0) * 2048 + swz;
    }
    const int ldst = r0 * 64 + p8 * 8;

    const float* brow = bias + (size_t)h * 2048 * 2048 + (size_t)(qw + quad * 4) * 2048 + l16;
    const float S2 = 0.18033688011112042f;   // 0.125 * log2(e)
    const float K2 = 1.4426950408889634f;    // log2(e)
    const float C2 = -11.541560327111707f;   // -8 * log2(e)

    // prefetch tile 0
#pragma unroll
    for (int bi = 0; bi < 2; ++bi) {
        gload_lds16(kg[bi], &Ks[0][bi][0] + ldst);
        gload_lds16(kg[bi] + 8 * 1024, &Ks[0][bi][512] + ldst);
        gload_lds16(vg[bi], &VTs[0][bi][0] + ldst);
        gload_lds16(vg[bi] + 8 * 2048, &VTs[0][bi][512] + ldst);
    }
    float bbf[4][4];
#pragma unroll
    for (int t = 0; t < 4; ++t)
#pragma unroll
        for (int r = 0; r < 4; ++r)
            bbf[t][r] = fmaf(brow[(size_t)r * 2048 + t * 16], K2, C2);

    const int sw7 = l16 & 7;
    for (int kt = 0; kt < 32; ++kt) {
        const int buf = kt & 1;
        __syncthreads();  // glds(kt) drained & visible; prev tile fully consumed
        if (kt < 31) {
#pragma unroll
            for (int bi = 0; bi < 2; ++bi) {
                const unsigned short* kg2 = kg[bi] + (size_t)(kt + 1) * 64 * 1024;
                const unsigned short* vg2 = vg[bi] + (kt + 1) * 64;
                gload_lds16(kg2, &Ks[buf ^ 1][bi][0] + ldst);
                gload_lds16(kg2 + 8 * 1024, &Ks[buf ^ 1][bi][512] + ldst);
                gload_lds16(vg2, &VTs[buf ^ 1][bi][0] + ldst);
                gload_lds16(vg2 + 8 * 2048, &VTs[buf ^ 1][bi][512] + ldst);
            }
        }
        // S = Q K^T -> exp -> P (both batches, shared bbf)
#pragma unroll
        for (int bi = 0; bi < 2; ++bi) {
#pragma unroll
            for (int t = 0; t < 4; ++t) {
                const unsigned short* krow = &Ks[buf][bi][(t * 16 + l16) * 64];
                bf16x8 kb0 = load_frag(krow + ((quad ^ sw7) * 8));
                bf16x8 kb1 = load_frag(krow + (((quad + 4) ^ sw7) * 8));
                f32x4 c = {};
                c = __builtin_amdgcn_mfma_f32_16x16x32_bf16(qf[bi][0], kb0, c, 0, 0, 0);
                c = __builtin_amdgcn_mfma_f32_16x16x32_bf16(qf[bi][1], kb1, c, 0, 0, 0);
#pragma unroll
                for (int r = 0; r < 4; ++r) {
                    float e = __builtin_amdgcn_exp2f(fmaf(c[r], S2, bbf[t][r]));
                    lsum[bi][r] += e;
                    int m = quad * 4 + r;
                    int phys = (t * 2 + (l16 >> 3)) ^ ((m >> 1) & 7);
                    Ps[bi][wave * 1024 + m * 64 + phys * 8 + (l16 & 7)] = f2bf(e);
                }
            }
        }
        __syncthreads();  // P visible
        // prefetch next tile's bias (shared by both batches; overlaps PV)
        if (kt < 31) {
            const float* b2 = brow + (size_t)(kt + 1) * 64;
#pragma unroll
            for (int t = 0; t < 4; ++t)
#pragma unroll
                for (int r = 0; r < 4; ++r)
                    bbf[t][r] = fmaf(b2[(size_t)r * 2048 + t * 16], K2, C2);
        }
        // O += P V (both batches)
#pragma unroll
        for (int bi = 0; bi < 2; ++bi) {
            const unsigned short* prow = &Ps[bi][wave * 1024 + l16 * 64];
            bf16x8 pa0 = load_frag(prow + ((quad ^ ((l16 >> 1) & 7)) * 8));
            bf16x8 pa1 = load_frag(prow + (((quad + 4) ^ ((l16 >> 1) & 7)) * 8));
#pragma unroll
            for (int t = 0; t < 4; ++t) {
                const unsigned short* vrow = &VTs[buf][bi][(t * 16 + l16) * 64];
                bf16x8 vb0 = load_frag(vrow + ((quad ^ sw7) * 8));
                bf16x8 vb1 = load_frag(vrow + (((quad + 4) ^ sw7) * 8));
                Oacc[bi][t] = __builtin_amdgcn_mfma_f32_16x16x32_bf16(pa0, vb0, Oacc[bi][t], 0, 0, 0);
                Oacc[bi][t] = __builtin_amdgcn_mfma_f32_16x16x32_bf16(pa1, vb1, Oacc[bi][t], 0, 0, 0);
            }
        }
    }

    // reduce row sums over 16 k-lanes, store O / l
#pragma unroll
    for (int off = 1; off < 16; off <<= 1)
#pragma unroll
        for (int bi = 0; bi < 2; ++bi)
#pragma unroll
            for (int r = 0; r < 4; ++r) lsum[bi][r] += __shfl_xor(lsum[bi][r], off, 64);
#pragma unroll
    for (int bi = 0; bi < 2; ++bi)
#pragma unroll
        for (int r = 0; r < 4; ++r) {
            float inv = 1.0f / lsum[bi][r];
            int qg = qw + quad * 4 + r;
            unsigned short* op = o + (size_t)((bp * 2 + bi) * 2048 + qg) * 512 + h * 64;
#pragma unroll
            for (int t = 0; t < 4; ++t) op[t * 16 + l16] = f2bf(Oacc[bi][t][r] * inv);
        }
}

extern "C" void kernel_launch(void* const* d_in, const int* in_sizes, int n_in,
                              void* d_out, int out_size, void* d_ws, size_t ws_size,
                              hipStream_t stream) {
    const float* x      = (const float*)d_in[0];
    const float* abias  = (const float*)d_in[1];
    const float* ln1_w  = (const float*)d_in[2];
    const float* ln1_b  = (const float*)d_in[3];
    const float* ln2_w  = (const float*)d_in[4];
    const float* ln2_b  = (const float*)d_in[5];
    const float* wq     = (const float*)d_in[6];
    const float* bq     = (const float*)d_in[7];
    const float* wk     = (const float*)d_in[8];
    const float* bk     = (const float*)d_in[9];
    const float* wv     = (const float*)d_in[10];
    const float* bv     = (const float*)d_in[11];
    const float* wo     = (const float*)d_in[12];
    const float* bo     = (const float*)d_in[13];
    const float* w1     = (const float*)d_in[14];
    const float* b1     = (const float*)d_in[15];
    const float* w2     = (const float*)d_in[16];
    const float* b2     = (const float*)d_in[17];
    float* out = (float*)d_out;

    char* ws = (char*)d_ws;
    unsigned short* wqkvT  = (unsigned short*)(ws + 0);          // [1536][512] bf16
    unsigned short* woT    = (unsigned short*)(ws + 1572864);    // [512][512]
    unsigned short* w1T    = (unsigned short*)(ws + 2097152);    // [2048][512]
    unsigned short* w2T    = (unsigned short*)(ws + 4194304);    // [512][2048]
    float*          biasqkv= (float*)(ws + 6291456);             // [1536]
    unsigned short* hbuf   = (unsigned short*)(ws + 6297600);    // [8192][512] bf16 (h / h2)
    unsigned short* qkbuf  = (unsigned short*)(ws + 14686208);   // [8192][1024] bf16 (Q|K)
    unsigned short* vTbuf  = (unsigned short*)(ws + 31463424);   // [4*512][2048] bf16 (V^T per b,h)
    unsigned short* o_attn = (unsigned short*)(ws + 39852032);   // [8192][512] bf16
    unsigned short* ff1    = (unsigned short*)(ws + 48240640);   // [8192][2048] bf16

    // weights transpose/cast + bias concat
    prep_kernel<<<3078, dim3(32, 8), 0, stream>>>(wq, wk, wv, wo, w1, w2, bq, bk, bv,
                                                  wqkvT, woT, w1T, w2T, biasqkv);
    // h = LN1(x)
    ln_kernel<<<2048, 256, 0, stream>>>(x, ln1_w, ln1_b, hbuf);
    // qkbuf/vT = h @ [wq|wk|wv] + biases  (V written transposed)
    gemm_qkv_k<<<dim3(12, 64), 256, 0, stream>>>(hbuf, wqkvT, biasqkv, qkbuf, vTbuf);
    // o_attn = attention(q,k,v, bias) — 2 batches per block share the bias tile
    attn_kernel<<<dim3(32, 8, 2), 256, 0, stream>>>(qkbuf, vTbuf, abias, o_attn);
    // out = x + o_attn @ wo + bo   (plain stores, residual fused)
    gemm_oproj<<<dim3(8, 64), 256, 0, stream>>>(o_attn, woT, bo, x, out);
    // h2 = LN2(out)
    ln_kernel<<<2048, 256, 0, stream>>>(out, ln2_w, ln2_b, hbuf);
    // ff1 = GELU(h2 @ w1 + b1)
    gemm_gelu_k<<<dim3(16, 64), 256, 0, stream>>>(hbuf, w1T, b1, ff1);
    // out += ff1 @ w2 + b2   (plain read-modify-write, no atomics)
    gemm_ff2<<<dim3(8, 64), 256, 0, stream>>>(ff1, w2T, b2, out);
}